// Round 1
// baseline (8228.861 us; speedup 1.0000x reference)
//
#include <hip/hip_runtime.h>
#include <hip/hip_bf16.h>
#include <math.h>

// Problem constants
#define BB 64
#define TT 512
#define EE 256
#define HH 256
#define KK 9
// gx rows = B*T = 32768, gx cols = 4H = 1024

__device__ __forceinline__ float sigm(float x) { return 1.0f / (1.0f + __expf(-x)); }

// ---------------------------------------------------------------------------
// zero_kernel: zero loss, preds, and feats rows with t >= len (masked region).
// grid = 65536 (feats) + 128 (preds) + 1 (loss) = 65665 blocks x 256
// ---------------------------------------------------------------------------
__global__ __launch_bounds__(256) void zero_kernel(float* __restrict__ out,
                                                   const int* __restrict__ lens) {
    int bid = blockIdx.x;
    if (bid < 65536) {
        int g = bid * 256 + threadIdx.x;     // feats element index [0, 16777216)
        int row = g >> 9;                    // (b,t) row
        int t = row & 511;
        int b = row >> 9;
        if (t >= lens[b]) out[32769 + g] = 0.0f;
    } else if (bid < 65536 + 128) {
        int p = (bid - 65536) * 256 + threadIdx.x;  // preds index [0, 32768)
        out[1 + p] = 0.0f;
    } else if (threadIdx.x == 0) {
        out[0] = 0.0f;
    }
}

// ---------------------------------------------------------------------------
// pack_kernel: Wp[(k*256 + j)*4 + r] = Whh[(r*256 + j)*256 + k]
// (transposed + gate-interleaved so LSTM lane j reads one float4 per k)
// grid = 512 x 256 (first 65536 ids: fwd, next: bwd)
// ---------------------------------------------------------------------------
__global__ __launch_bounds__(256) void pack_kernel(const float* __restrict__ WhhF,
                                                   const float* __restrict__ WhhB,
                                                   float* __restrict__ WpF,
                                                   float* __restrict__ WpB) {
    int id = blockIdx.x * 256 + threadIdx.x;
    const float* src = WhhF;
    float* dst = WpF;
    if (id >= 65536) { id -= 65536; src = WhhB; dst = WpB; }
    int k = id & 255;
    int j = id >> 8;
#pragma unroll
    for (int r = 0; r < 4; ++r)
        dst[((k << 8) + j) * 4 + r] = src[((r << 8) + j) * 256 + k];
}

// ---------------------------------------------------------------------------
// gemm_gx: gx[row][g] = sum_e word_vec[widx[row]][e] * Wih[g][e] + bias[g]
// 64x64 tile, BK=16, 256 threads, 4x4 per thread. Skips tiles fully beyond len.
// grid = (512, 16)
// ---------------------------------------------------------------------------
__global__ __launch_bounds__(256) void gemm_gx_kernel(const int* __restrict__ widx,
                                                      const int* __restrict__ lens,
                                                      const float* __restrict__ wvec,
                                                      const float* __restrict__ Wih,
                                                      const float* __restrict__ bias,
                                                      float* __restrict__ gx) {
    int row0 = blockIdx.x * 64;
    int b = row0 >> 9;
    int t0 = row0 & 511;
    if (t0 >= lens[b]) return;  // whole tile masked -> gx rows never read
    int n0 = blockIdx.y * 64;

    __shared__ __align__(16) float As[16][68];  // pad 4: conflict-free + 16B-aligned float4
    __shared__ __align__(16) float Bs[16][68];
    __shared__ int aoff[64];

    int tid = threadIdx.x;
    if (tid < 64) aoff[tid] = widx[row0 + tid] << 8;  // * E
    __syncthreads();

    float acc[4][4] = {};
    int tn = tid & 15, tm = tid >> 4;

    for (int k0 = 0; k0 < 256; k0 += 16) {
#pragma unroll
        for (int p = 0; p < 4; ++p) {
            int lin = p * 256 + tid;
            int k = lin & 15, m = lin >> 4;
            As[k][m] = wvec[aoff[m] + k0 + k];
            Bs[k][m] = Wih[((n0 + m) << 8) + k0 + k];
        }
        __syncthreads();
#pragma unroll
        for (int k = 0; k < 16; ++k) {
            float4 av = *reinterpret_cast<const float4*>(&As[k][tm * 4]);
            float4 bv = *reinterpret_cast<const float4*>(&Bs[k][tn * 4]);
            float am[4] = {av.x, av.y, av.z, av.w};
            float bn[4] = {bv.x, bv.y, bv.z, bv.w};
#pragma unroll
            for (int i = 0; i < 4; ++i)
#pragma unroll
                for (int j = 0; j < 4; ++j) acc[i][j] = fmaf(am[i], bn[j], acc[i][j]);
        }
        __syncthreads();
    }

#pragma unroll
    for (int i = 0; i < 4; ++i) {
        int row = row0 + tm * 4 + i;
        float4 o;
        o.x = acc[i][0] + bias[n0 + tn * 4 + 0];
        o.y = acc[i][1] + bias[n0 + tn * 4 + 1];
        o.z = acc[i][2] + bias[n0 + tn * 4 + 2];
        o.w = acc[i][3] + bias[n0 + tn * 4 + 3];
        *reinterpret_cast<float4*>(&gx[row * 1024 + n0 + tn * 4]) = o;
    }
}

// ---------------------------------------------------------------------------
// lstm_kernel: one block per (batch, direction); 256 threads; thread j owns
// gate index j -> c_j in a register, h in LDS. Runs only t < len (exact: masked
// steps never influence unmasked outputs). Writes h into the feats output
// half (fwd -> cols [0,256), bwd -> cols [256,512) at original position).
// ---------------------------------------------------------------------------
__global__ __launch_bounds__(256) void lstm_kernel(const float* __restrict__ gx0,
                                                   const float* __restrict__ gx1,
                                                   const float* __restrict__ Wp0,
                                                   const float* __restrict__ Wp1,
                                                   const int* __restrict__ lens,
                                                   float* __restrict__ feats,
                                                   int two_dirs, int dir0) {
    int dir, b;
    if (two_dirs) { dir = blockIdx.x & 1; b = blockIdx.x >> 1; }
    else          { dir = dir0;           b = blockIdx.x; }
    const float* gx = dir ? gx1 : gx0;
    const float4* Wp4 = reinterpret_cast<const float4*>(dir ? Wp1 : Wp0);
    int len = lens[b];
    int tid = threadIdx.x;

    __shared__ float hs[256];
    hs[tid] = 0.0f;
    __syncthreads();
    float c = 0.0f;

    for (int tp = 0; tp < len; ++tp) {
        int t = dir ? (len - 1 - tp) : tp;
        const float* gr = gx + ((b << 9) + t) * 1024;
        float a0 = gr[tid];
        float a1 = gr[256 + tid];
        float a2 = gr[512 + tid];
        float a3 = gr[768 + tid];
#pragma unroll 8
        for (int k = 0; k < 256; ++k) {
            float hk = hs[k];                      // LDS broadcast
            float4 w = Wp4[(k << 8) + tid];        // coalesced 16B/lane
            a0 = fmaf(hk, w.x, a0);
            a1 = fmaf(hk, w.y, a1);
            a2 = fmaf(hk, w.z, a2);
            a3 = fmaf(hk, w.w, a3);
        }
        float ig = sigm(a0);
        float fg = sigm(a1);
        float gg = tanhf(a2);
        float og = sigm(a3);
        c = fg * c + ig * gg;
        float h = og * tanhf(c);
        __syncthreads();        // all reads of old hs done
        hs[tid] = h;
        feats[((b << 9) + t) * 512 + (dir ? 256 : 0) + tid] = h;
        __syncthreads();        // new hs visible
    }
}

// ---------------------------------------------------------------------------
// emis_kernel: emissions[b,t,k] = feats[b,t,:] . W_out[k,:] + b_out[k]
// one wave per (b,t) row; skip masked rows.
// ---------------------------------------------------------------------------
__global__ __launch_bounds__(64) void emis_kernel(const float* __restrict__ feats,
                                                  const float* __restrict__ Wout,
                                                  const float* __restrict__ bout,
                                                  const int* __restrict__ lens,
                                                  float* __restrict__ emis) {
    int r = blockIdx.x;
    int b = r >> 9, t = r & 511;
    if (t >= lens[b]) return;
    int lane = threadIdx.x;
    const float* fr = feats + r * 512;
    float f[8];
#pragma unroll
    for (int i = 0; i < 8; ++i) f[i] = fr[i * 64 + lane];
#pragma unroll
    for (int k = 0; k < 9; ++k) {
        float p = 0.0f;
#pragma unroll
        for (int i = 0; i < 8; ++i) p = fmaf(f[i], Wout[k * 512 + i * 64 + lane], p);
#pragma unroll
        for (int off = 32; off; off >>= 1) p += __shfl_down(p, off);
        if (lane == 0) emis[r * 9 + k] = p + bout[k];
    }
}

// ---------------------------------------------------------------------------
// crf_kernel: per batch: alpha recursion (logsumexp), viterbi + LDS history +
// backtrace, numerator score (wave-parallel), loss via atomicAdd, preds write.
// 64 blocks x 64 threads (lanes 0..8 carry the K=9 state).
// ---------------------------------------------------------------------------
__global__ __launch_bounds__(64) void crf_kernel(const float* __restrict__ emis,
                                                 const int* __restrict__ lens,
                                                 const int* __restrict__ labels,
                                                 const float* __restrict__ start_trans,
                                                 const float* __restrict__ end_trans,
                                                 const float* __restrict__ trans,
                                                 float* __restrict__ out) {
    int b = blockIdx.x;
    int len = lens[b];
    int lane = threadIdx.x;
    __shared__ float alpha[9], vit[9];
    __shared__ unsigned char hist[512 * 9];
    const float* eb = emis + b * 512 * 9;
    const int* lb = labels + b * 512;

    float tr[9];
    if (lane < 9) {
#pragma unroll
        for (int i = 0; i < 9; ++i) tr[i] = trans[i * 9 + lane];  // column `lane`
        float s0 = start_trans[lane] + eb[lane];
        alpha[lane] = s0;
        vit[lane] = s0;
    }
    __syncthreads();

    for (int t = 1; t < len; ++t) {
        float na = 0.0f, nv = 0.0f;
        int best = 0;
        if (lane < 9) {
            float e = eb[t * 9 + lane];
            float a[9];
#pragma unroll
            for (int i = 0; i < 9; ++i) a[i] = alpha[i] + tr[i];
            float m = a[0];
#pragma unroll
            for (int i = 1; i < 9; ++i) m = fmaxf(m, a[i]);
            float s = 0.0f;
#pragma unroll
            for (int i = 0; i < 9; ++i) s += __expf(a[i] - m);
            na = m + __logf(s) + e;
            float bv = vit[0] + tr[0];
            int bi = 0;
#pragma unroll
            for (int i = 1; i < 9; ++i) {
                float x = vit[i] + tr[i];
                if (x > bv) { bv = x; bi = i; }   // strict > == first-max (jnp.argmax)
            }
            nv = bv + e;
            best = bi;
            hist[t * 9 + lane] = (unsigned char)best;
        }
        __syncthreads();
        if (lane < 9) { alpha[lane] = na; vit[lane] = nv; }
        __syncthreads();
    }

    // numerator: wave-parallel over t
    float part = 0.0f;
    for (int t = 1 + lane; t < len; t += 64) {
        int yp = lb[t - 1], y = lb[t];
        part += trans[yp * 9 + y] + eb[t * 9 + y];
    }
#pragma unroll
    for (int off = 32; off; off >>= 1) part += __shfl_down(part, off);

    if (lane == 0) {
        int y0 = lb[0];
        float num = start_trans[y0] + eb[y0] + part + end_trans[lb[len - 1]];
        float m = alpha[0] + end_trans[0];
        for (int j = 1; j < 9; ++j) m = fmaxf(m, alpha[j] + end_trans[j]);
        float s = 0.0f;
        for (int j = 0; j < 9; ++j) s += __expf(alpha[j] + end_trans[j] - m);
        float denom = m + __logf(s);
        atomicAdd(out, (denom - num) * (1.0f / 64.0f));  // ner_loss = -mean(num-denom)

        float bm = vit[0] + end_trans[0];
        int cur = 0;
        for (int j = 1; j < 9; ++j) {
            float x = vit[j] + end_trans[j];
            if (x > bm) { bm = x; cur = j; }
        }
        float* preds = out + 1 + b * 512;
        preds[len - 1] = (float)cur;
        for (int t = len - 1; t >= 1; --t) {
            cur = hist[t * 9 + cur];
            preds[t - 1] = (float)cur;
        }
    }
}

// ---------------------------------------------------------------------------
extern "C" void kernel_launch(void* const* d_in, const int* in_sizes, int n_in,
                              void* d_out, int out_size, void* d_ws, size_t ws_size,
                              hipStream_t stream) {
    const int* widx = (const int*)d_in[0];
    const int* lens = (const int*)d_in[1];
    const int* labels = (const int*)d_in[2];
    const float* wvec = (const float*)d_in[3];
    const float* WihF = (const float*)d_in[4];
    const float* WhhF = (const float*)d_in[5];
    const float* bF = (const float*)d_in[6];
    const float* WihB = (const float*)d_in[7];
    const float* WhhB = (const float*)d_in[8];
    const float* bB = (const float*)d_in[9];
    const float* Wout = (const float*)d_in[10];
    const float* bout = (const float*)d_in[11];
    const float* start_trans = (const float*)d_in[12];
    const float* end_trans = (const float*)d_in[13];
    const float* trans = (const float*)d_in[14];
    float* out = (float*)d_out;
    float* ws = (float*)d_ws;

    // workspace layout (floats)
    float* gxF = ws;                    // 33554432  (B*T*1024)
    float* WpF = gxF + 33554432;        // 262144
    float* WpB = WpF + 262144;          // 262144
    float* emis = WpB + 262144;         // 294912    (B*T*9)
    float* gxB = emis + 294912;         // optional second gx buffer
    const size_t need1 = (size_t)(33554432 + 262144 + 262144 + 294912) * 4;
    const size_t need2 = need1 + (size_t)33554432 * 4;
    bool dual = ws_size >= need2;       // deterministic across calls

    float* feats = out + 1 + 32768;     // feats output region (B,T,512)

    zero_kernel<<<65665, 256, 0, stream>>>(out, lens);
    pack_kernel<<<512, 256, 0, stream>>>(WhhF, WhhB, WpF, WpB);

    dim3 ggrid(512, 16);
    if (dual) {
        gemm_gx_kernel<<<ggrid, 256, 0, stream>>>(widx, lens, wvec, WihF, bF, gxF);
        gemm_gx_kernel<<<ggrid, 256, 0, stream>>>(widx, lens, wvec, WihB, bB, gxB);
        lstm_kernel<<<128, 256, 0, stream>>>(gxF, gxB, WpF, WpB, lens, feats, 1, 0);
    } else {
        gemm_gx_kernel<<<ggrid, 256, 0, stream>>>(widx, lens, wvec, WihF, bF, gxF);
        lstm_kernel<<<64, 256, 0, stream>>>(gxF, gxF, WpF, WpB, lens, feats, 0, 0);
        gemm_gx_kernel<<<ggrid, 256, 0, stream>>>(widx, lens, wvec, WihB, bB, gxF);
        lstm_kernel<<<64, 256, 0, stream>>>(gxF, gxF, WpF, WpB, lens, feats, 0, 1);
    }
    emis_kernel<<<32768, 64, 0, stream>>>(feats, Wout, bout, lens, emis);
    crf_kernel<<<64, 64, 0, stream>>>(emis, lens, labels, start_trans, end_trans, trans, out);
}

// Round 2
// 2569.659 us; speedup vs baseline: 3.2023x; 3.2023x over previous
//
#include <hip/hip_runtime.h>
#include <hip/hip_bf16.h>
#include <math.h>

#ifndef __has_builtin
#define __has_builtin(x) 0
#endif

typedef unsigned int uint;
typedef unsigned short ushort;
typedef _Float16 half2_t __attribute__((ext_vector_type(2)));

// Problem constants: B=64, T=512, V=30000, E=256, H=256, K=9. 4H = 1024.

__device__ __forceinline__ float sigm(float x) {
    return __fdividef(1.0f, 1.0f + __expf(-x));
}
__device__ __forceinline__ float tanh_fast(float x) {
    // abs-error ~1e-7; clamp prevents exp overflow (c can grow ~len)
    float xc = fminf(fmaxf(x, -12.0f), 12.0f);
    float e = __expf(2.0f * xc);
    return __fdividef(e - 1.0f, e + 1.0f);
}
__device__ __forceinline__ float dot2f(uint w, uint h, float acc) {
#if __has_builtin(__builtin_amdgcn_fdot2)
    return __builtin_amdgcn_fdot2(__builtin_bit_cast(half2_t, w),
                                  __builtin_bit_cast(half2_t, h), acc, false);
#else
    half2_t a = __builtin_bit_cast(half2_t, w);
    half2_t b = __builtin_bit_cast(half2_t, h);
    return acc + (float)a.x * (float)b.x + (float)a.y * (float)b.y;
#endif
}

// ---------------------------------------------------------------------------
// zero_kernel: zero loss, preds, and feats rows with t >= len (masked region).
// ---------------------------------------------------------------------------
__global__ __launch_bounds__(256) void zero_kernel(float* __restrict__ out,
                                                   const int* __restrict__ lens) {
    int bid = blockIdx.x;
    if (bid < 65536) {
        int g = bid * 256 + threadIdx.x;     // feats element [0, 16777216)
        int row = g >> 9;
        int t = row & 511;
        int b = row >> 9;
        if (t >= lens[b]) out[32769 + g] = 0.0f;
    } else if (bid < 65536 + 128) {
        int p = (bid - 65536) * 256 + threadIdx.x;
        out[1 + p] = 0.0f;
    } else if (threadIdx.x == 0) {
        out[0] = 0.0f;
    }
}

// ---------------------------------------------------------------------------
// pack_kernel: W_hh (4H,H) fp32 -> fp16 k-pair-packed, two layouts:
//   reg chunk  (k-pairs m in [0,96)):  wreg[(q*96+m)*256 + j] = (W[g][2m], W[g][2m+1])
//   LDS chunk  (m in [96,128)):        wlds[(m-96)*1024 + j*4 + q]
// where g = q*256 + j (q = gate i/f/g/o, j = hidden index).
// grid = 1024 x 256 (first half fwd, second half bwd)
// ---------------------------------------------------------------------------
__global__ __launch_bounds__(256) void pack_kernel(const float* __restrict__ WF,
                                                   const float* __restrict__ WB,
                                                   uint* __restrict__ wregF,
                                                   uint* __restrict__ wregB,
                                                   uint* __restrict__ wldsF,
                                                   uint* __restrict__ wldsB) {
    int id = blockIdx.x * 256 + threadIdx.x;   // 0..262143
    const float* W = WF; uint* wr = wregF; uint* wl = wldsF;
    if (id >= 131072) { id -= 131072; W = WB; wr = wregB; wl = wldsB; }
    int m = id & 127;          // k-pair index (lanes vary m -> coalesced reads)
    int g = id >> 7;           // gate row 0..1023
    int q = g >> 8, j = g & 255;
    float f0 = W[g * 256 + 2 * m];
    float f1 = W[g * 256 + 2 * m + 1];
    ushort u0 = __builtin_bit_cast(ushort, (_Float16)f0);
    ushort u1 = __builtin_bit_cast(ushort, (_Float16)f1);
    uint pk = (uint)u0 | ((uint)u1 << 16);
    if (m < 96) wr[(q * 96 + m) * 256 + j] = pk;
    else        wl[(m - 96) * 1024 + j * 4 + q] = pk;
}

// ---------------------------------------------------------------------------
// gemm_gx: gx[row][g] = sum_e word_vec[widx[row]][e] * Wih[g][e] + bias[g]
// fp32 compute, fp16 output. 64x64 tile, BK=16, 4x4/thread. Skips masked tiles.
// grid = (512, 16)
// ---------------------------------------------------------------------------
__global__ __launch_bounds__(256) void gemm_gx_kernel(const int* __restrict__ widx,
                                                      const int* __restrict__ lens,
                                                      const float* __restrict__ wvec,
                                                      const float* __restrict__ Wih,
                                                      const float* __restrict__ bias,
                                                      _Float16* __restrict__ gx) {
    int row0 = blockIdx.x * 64;
    int b = row0 >> 9;
    int t0 = row0 & 511;
    if (t0 >= lens[b]) return;
    int n0 = blockIdx.y * 64;

    __shared__ __align__(16) float As[16][68];
    __shared__ __align__(16) float Bs[16][68];
    __shared__ int aoff[64];

    int tid = threadIdx.x;
    if (tid < 64) aoff[tid] = widx[row0 + tid] << 8;
    __syncthreads();

    float acc[4][4] = {};
    int tn = tid & 15, tm = tid >> 4;

    for (int k0 = 0; k0 < 256; k0 += 16) {
#pragma unroll
        for (int p = 0; p < 4; ++p) {
            int lin = p * 256 + tid;
            int k = lin & 15, m = lin >> 4;
            As[k][m] = wvec[aoff[m] + k0 + k];
            Bs[k][m] = Wih[((n0 + m) << 8) + k0 + k];
        }
        __syncthreads();
#pragma unroll
        for (int k = 0; k < 16; ++k) {
            float4 av = *reinterpret_cast<const float4*>(&As[k][tm * 4]);
            float4 bv = *reinterpret_cast<const float4*>(&Bs[k][tn * 4]);
            float am[4] = {av.x, av.y, av.z, av.w};
            float bn[4] = {bv.x, bv.y, bv.z, bv.w};
#pragma unroll
            for (int i = 0; i < 4; ++i)
#pragma unroll
                for (int j = 0; j < 4; ++j) acc[i][j] = fmaf(am[i], bn[j], acc[i][j]);
        }
        __syncthreads();
    }

#pragma unroll
    for (int i = 0; i < 4; ++i) {
        int row = row0 + tm * 4 + i;
        ushort u0 = __builtin_bit_cast(ushort, (_Float16)(acc[i][0] + bias[n0 + tn * 4 + 0]));
        ushort u1 = __builtin_bit_cast(ushort, (_Float16)(acc[i][1] + bias[n0 + tn * 4 + 1]));
        ushort u2 = __builtin_bit_cast(ushort, (_Float16)(acc[i][2] + bias[n0 + tn * 4 + 2]));
        ushort u3 = __builtin_bit_cast(ushort, (_Float16)(acc[i][3] + bias[n0 + tn * 4 + 3]));
        uint2 st;
        st.x = (uint)u0 | ((uint)u1 << 16);
        st.y = (uint)u2 | ((uint)u3 << 16);
        *reinterpret_cast<uint2*>(&gx[row * 1024 + n0 + tn * 4]) = st;
    }
}

// ---------------------------------------------------------------------------
// lstm_kernel: one block per (b, dir); 128 blocks, 256 threads; thread j owns
// gates (j, 256+j, 512+j, 768+j) and h[j]. W_hh fp16 fully RESIDENT:
// 96 k-pair rows in VGPRs (384 regs) + 32 k-pair rows in LDS (128 KB).
// h kept fp16-packed in LDS (double-buffered: one barrier/step); inner loop
// is v_dot2_f32_f16 (fp32 accumulate). Zero steady-state W traffic.
// ---------------------------------------------------------------------------
__global__ __launch_bounds__(256, 1) void lstm_kernel(const _Float16* __restrict__ gx0,
                                                      const _Float16* __restrict__ gx1,
                                                      const uint* __restrict__ wreg0,
                                                      const uint* __restrict__ wreg1,
                                                      const uint* __restrict__ wlds0,
                                                      const uint* __restrict__ wlds1,
                                                      const int* __restrict__ lens,
                                                      float* __restrict__ feats) {
    int dir = blockIdx.x & 1;
    int b = blockIdx.x >> 1;
    const _Float16* gx = dir ? gx1 : gx0;
    const uint* wreg = dir ? wreg1 : wreg0;
    const uint* wlds = dir ? wlds1 : wlds0;
    int len = lens[b];
    int tid = threadIdx.x;

    __shared__ __align__(16) uint lw[32 * 1024];      // 128 KB W chunk
    __shared__ __align__(16) ushort hbuf[2][256];     // fp16 h, double-buffered

    // stage LDS W chunk (once)
    for (int i = tid; i < 32768; i += 256) lw[i] = wlds[i];

    // stage register W chunk (once): 4 gates x 96 k-pairs
    uint wr0[96], wr1[96], wr2[96], wr3[96];
#pragma unroll
    for (int m = 0; m < 96; ++m) {
        wr0[m] = wreg[(m) * 256 + tid];
        wr1[m] = wreg[(96 + m) * 256 + tid];
        wr2[m] = wreg[(192 + m) * 256 + tid];
        wr3[m] = wreg[(288 + m) * 256 + tid];
    }

    hbuf[0][tid] = 0;   // fp16 +0
    float c = 0.0f;
    __syncthreads();

    int p = 0;
    for (int tp = 0; tp < len; ++tp) {
        int t = dir ? (len - 1 - tp) : tp;
        const _Float16* gr = gx + (size_t)(((b << 9) + t)) * 1024;
        float a0 = (float)gr[tid];
        float a1 = (float)gr[256 + tid];
        float a2 = (float)gr[512 + tid];
        float a3 = (float)gr[768 + tid];

        const uint* hp = reinterpret_cast<const uint*>(hbuf[p]);

        // register-resident rows: k-pairs 0..95
#pragma unroll
        for (int i = 0; i < 24; ++i) {
            uint4 hb = *reinterpret_cast<const uint4*>(hp + i * 4);
            int m = i * 4;
            a0 = dot2f(wr0[m + 0], hb.x, a0); a1 = dot2f(wr1[m + 0], hb.x, a1);
            a2 = dot2f(wr2[m + 0], hb.x, a2); a3 = dot2f(wr3[m + 0], hb.x, a3);
            a0 = dot2f(wr0[m + 1], hb.y, a0); a1 = dot2f(wr1[m + 1], hb.y, a1);
            a2 = dot2f(wr2[m + 1], hb.y, a2); a3 = dot2f(wr3[m + 1], hb.y, a3);
            a0 = dot2f(wr0[m + 2], hb.z, a0); a1 = dot2f(wr1[m + 2], hb.z, a1);
            a2 = dot2f(wr2[m + 2], hb.z, a2); a3 = dot2f(wr3[m + 2], hb.z, a3);
            a0 = dot2f(wr0[m + 3], hb.w, a0); a1 = dot2f(wr1[m + 3], hb.w, a1);
            a2 = dot2f(wr2[m + 3], hb.w, a2); a3 = dot2f(wr3[m + 3], hb.w, a3);
        }
        // LDS-resident rows: k-pairs 96..127 (ds_read_b128, 16B/thread/row)
#pragma unroll
        for (int i = 0; i < 8; ++i) {
            uint4 hb = *reinterpret_cast<const uint4*>(hp + 96 + i * 4);
            const uint4 w0 = *reinterpret_cast<const uint4*>(&lw[(i * 4 + 0) * 1024 + (tid << 2)]);
            a0 = dot2f(w0.x, hb.x, a0); a1 = dot2f(w0.y, hb.x, a1);
            a2 = dot2f(w0.z, hb.x, a2); a3 = dot2f(w0.w, hb.x, a3);
            const uint4 w1 = *reinterpret_cast<const uint4*>(&lw[(i * 4 + 1) * 1024 + (tid << 2)]);
            a0 = dot2f(w1.x, hb.y, a0); a1 = dot2f(w1.y, hb.y, a1);
            a2 = dot2f(w1.z, hb.y, a2); a3 = dot2f(w1.w, hb.y, a3);
            const uint4 w2 = *reinterpret_cast<const uint4*>(&lw[(i * 4 + 2) * 1024 + (tid << 2)]);
            a0 = dot2f(w2.x, hb.z, a0); a1 = dot2f(w2.y, hb.z, a1);
            a2 = dot2f(w2.z, hb.z, a2); a3 = dot2f(w2.w, hb.z, a3);
            const uint4 w3 = *reinterpret_cast<const uint4*>(&lw[(i * 4 + 3) * 1024 + (tid << 2)]);
            a0 = dot2f(w3.x, hb.w, a0); a1 = dot2f(w3.y, hb.w, a1);
            a2 = dot2f(w3.z, hb.w, a2); a3 = dot2f(w3.w, hb.w, a3);
        }

        float ig = sigm(a0);
        float fg = sigm(a1);
        float gg = tanh_fast(a2);
        float og = sigm(a3);
        c = fg * c + ig * gg;
        float h = og * tanh_fast(c);

        hbuf[p ^ 1][tid] = __builtin_bit_cast(ushort, (_Float16)h);
        feats[(size_t)(((b << 9) + t)) * 512 + (dir << 8) + tid] = h;
        __syncthreads();   // new h visible; old buffer free next step
        p ^= 1;
    }
}

// ---------------------------------------------------------------------------
// emis_kernel: emissions[b,t,k] = feats[b,t,:] . W_out[k,:] + b_out[k]
// ---------------------------------------------------------------------------
__global__ __launch_bounds__(64) void emis_kernel(const float* __restrict__ feats,
                                                  const float* __restrict__ Wout,
                                                  const float* __restrict__ bout,
                                                  const int* __restrict__ lens,
                                                  float* __restrict__ emis) {
    int r = blockIdx.x;
    int b = r >> 9, t = r & 511;
    if (t >= lens[b]) return;
    int lane = threadIdx.x;
    const float* fr = feats + (size_t)r * 512;
    float f[8];
#pragma unroll
    for (int i = 0; i < 8; ++i) f[i] = fr[i * 64 + lane];
#pragma unroll
    for (int k = 0; k < 9; ++k) {
        float p = 0.0f;
#pragma unroll
        for (int i = 0; i < 8; ++i) p = fmaf(f[i], Wout[k * 512 + i * 64 + lane], p);
#pragma unroll
        for (int off = 32; off; off >>= 1) p += __shfl_down(p, off);
        if (lane == 0) emis[r * 9 + k] = p + bout[k];
    }
}

// ---------------------------------------------------------------------------
// crf_kernel: alpha recursion + viterbi + backtrace + numerator + loss.
// ---------------------------------------------------------------------------
__global__ __launch_bounds__(64) void crf_kernel(const float* __restrict__ emis,
                                                 const int* __restrict__ lens,
                                                 const int* __restrict__ labels,
                                                 const float* __restrict__ start_trans,
                                                 const float* __restrict__ end_trans,
                                                 const float* __restrict__ trans,
                                                 float* __restrict__ out) {
    int b = blockIdx.x;
    int len = lens[b];
    int lane = threadIdx.x;
    __shared__ float alpha[9], vit[9];
    __shared__ unsigned char hist[512 * 9];
    const float* eb = emis + b * 512 * 9;
    const int* lb = labels + b * 512;

    float tr[9];
    if (lane < 9) {
#pragma unroll
        for (int i = 0; i < 9; ++i) tr[i] = trans[i * 9 + lane];
        float s0 = start_trans[lane] + eb[lane];
        alpha[lane] = s0;
        vit[lane] = s0;
    }
    __syncthreads();

    for (int t = 1; t < len; ++t) {
        float na = 0.0f, nv = 0.0f;
        if (lane < 9) {
            float e = eb[t * 9 + lane];
            float a[9];
#pragma unroll
            for (int i = 0; i < 9; ++i) a[i] = alpha[i] + tr[i];
            float m = a[0];
#pragma unroll
            for (int i = 1; i < 9; ++i) m = fmaxf(m, a[i]);
            float s = 0.0f;
#pragma unroll
            for (int i = 0; i < 9; ++i) s += __expf(a[i] - m);
            na = m + __logf(s) + e;
            float bv = vit[0] + tr[0];
            int bi = 0;
#pragma unroll
            for (int i = 1; i < 9; ++i) {
                float x = vit[i] + tr[i];
                if (x > bv) { bv = x; bi = i; }
            }
            nv = bv + e;
            hist[t * 9 + lane] = (unsigned char)bi;
        }
        __syncthreads();
        if (lane < 9) { alpha[lane] = na; vit[lane] = nv; }
        __syncthreads();
    }

    float part = 0.0f;
    for (int t = 1 + lane; t < len; t += 64) {
        int yp = lb[t - 1], y = lb[t];
        part += trans[yp * 9 + y] + eb[t * 9 + y];
    }
#pragma unroll
    for (int off = 32; off; off >>= 1) part += __shfl_down(part, off);

    if (lane == 0) {
        int y0 = lb[0];
        float num = start_trans[y0] + eb[y0] + part + end_trans[lb[len - 1]];
        float m = alpha[0] + end_trans[0];
        for (int j = 1; j < 9; ++j) m = fmaxf(m, alpha[j] + end_trans[j]);
        float s = 0.0f;
        for (int j = 0; j < 9; ++j) s += __expf(alpha[j] + end_trans[j] - m);
        float denom = m + __logf(s);
        atomicAdd(out, (denom - num) * (1.0f / 64.0f));

        float bm = vit[0] + end_trans[0];
        int cur = 0;
        for (int j = 1; j < 9; ++j) {
            float x = vit[j] + end_trans[j];
            if (x > bm) { bm = x; cur = j; }
        }
        float* preds = out + 1 + b * 512;
        preds[len - 1] = (float)cur;
        for (int t = len - 1; t >= 1; --t) {
            cur = hist[t * 9 + cur];
            preds[t - 1] = (float)cur;
        }
    }
}

// ---------------------------------------------------------------------------
extern "C" void kernel_launch(void* const* d_in, const int* in_sizes, int n_in,
                              void* d_out, int out_size, void* d_ws, size_t ws_size,
                              hipStream_t stream) {
    const int* widx = (const int*)d_in[0];
    const int* lens = (const int*)d_in[1];
    const int* labels = (const int*)d_in[2];
    const float* wvec = (const float*)d_in[3];
    const float* WihF = (const float*)d_in[4];
    const float* WhhF = (const float*)d_in[5];
    const float* bF = (const float*)d_in[6];
    const float* WihB = (const float*)d_in[7];
    const float* WhhB = (const float*)d_in[8];
    const float* bB = (const float*)d_in[9];
    const float* Wout = (const float*)d_in[10];
    const float* bout = (const float*)d_in[11];
    const float* start_trans = (const float*)d_in[12];
    const float* end_trans = (const float*)d_in[13];
    const float* trans = (const float*)d_in[14];
    float* out = (float*)d_out;
    char* ws = (char*)d_ws;

    // workspace layout (bytes) — total 136,445,952 < proven-safe 137,486,336
    _Float16* gxF = (_Float16*)(ws);                        // 67,108,864 B
    _Float16* gxB = (_Float16*)(ws + 67108864);             // 67,108,864 B
    uint* wregF   = (uint*)(ws + 134217728);                // 393,216 B
    uint* wregB   = (uint*)(ws + 134610944);                // 393,216 B
    uint* wldsF   = (uint*)(ws + 135004160);                // 131,072 B
    uint* wldsB   = (uint*)(ws + 135135232);                // 131,072 B
    float* emis   = (float*)(ws + 135266304);               // 1,179,648 B
    (void)in_sizes; (void)n_in; (void)out_size; (void)ws_size;

    float* feats = out + 1 + 32768;   // feats output region (B,T,512) fp32

    zero_kernel<<<65665, 256, 0, stream>>>(out, lens);
    pack_kernel<<<1024, 256, 0, stream>>>(WhhF, WhhB, wregF, wregB, wldsF, wldsB);

    dim3 ggrid(512, 16);
    gemm_gx_kernel<<<ggrid, 256, 0, stream>>>(widx, lens, wvec, WihF, bF, gxF);
    gemm_gx_kernel<<<ggrid, 256, 0, stream>>>(widx, lens, wvec, WihB, bB, gxB);

    lstm_kernel<<<128, 256, 0, stream>>>(gxF, gxB, wregF, wregB, wldsF, wldsB, lens, feats);

    emis_kernel<<<32768, 64, 0, stream>>>(feats, Wout, bout, lens, emis);
    crf_kernel<<<64, 64, 0, stream>>>(emis, lens, labels, start_trans, end_trans, trans, out);
}

// Round 3
// 2214.136 us; speedup vs baseline: 3.7165x; 1.1606x over previous
//
#include <hip/hip_runtime.h>
#include <hip/hip_bf16.h>
#include <math.h>

#ifndef __has_builtin
#define __has_builtin(x) 0
#endif

typedef unsigned int uint;
typedef unsigned short ushort;
typedef _Float16 half2_t __attribute__((ext_vector_type(2)));

// Problem constants: B=64, T=512, V=30000, E=256, H=256, K=9. 4H = 1024.

__device__ __forceinline__ float sigm(float x) {
    return __fdividef(1.0f, 1.0f + __expf(-x));
}
__device__ __forceinline__ float tanh_fast(float x) {
    float xc = fminf(fmaxf(x, -12.0f), 12.0f);
    float e = __expf(2.0f * xc);
    return __fdividef(e - 1.0f, e + 1.0f);
}
__device__ __forceinline__ float dot2f(uint w, uint h, float acc) {
#if __has_builtin(__builtin_amdgcn_fdot2)
    return __builtin_amdgcn_fdot2(__builtin_bit_cast(half2_t, w),
                                  __builtin_bit_cast(half2_t, h), acc, false);
#else
    half2_t a = __builtin_bit_cast(half2_t, w);
    half2_t b = __builtin_bit_cast(half2_t, h);
    return acc + (float)a.x * (float)b.x + (float)a.y * (float)b.y;
#endif
}

// ---------------------------------------------------------------------------
// zero_kernel: zero loss, preds, and feats rows with t >= len (masked region).
// ---------------------------------------------------------------------------
__global__ __launch_bounds__(256) void zero_kernel(float* __restrict__ out,
                                                   const int* __restrict__ lens) {
    int bid = blockIdx.x;
    if (bid < 65536) {
        int g = bid * 256 + threadIdx.x;
        int row = g >> 9;
        int t = row & 511;
        int b = row >> 9;
        if (t >= lens[b]) out[32769 + g] = 0.0f;
    } else if (bid < 65536 + 128) {
        int p = (bid - 65536) * 256 + threadIdx.x;
        out[1 + p] = 0.0f;
    } else if (threadIdx.x == 0) {
        out[0] = 0.0f;
    }
}

// ---------------------------------------------------------------------------
// pack_kernel: W_hh (4H,H) fp32 -> fp16 k-pair-packed, two layouts:
//   reg chunk (k-pairs m in [0,96)):  wreg[(q*96+m)*256 + j] = (W[g][2m],W[g][2m+1])
//   LDS chunk (m in [96,128)):        wlds[(m-96)*1024 + j*4 + q]
// g = q*256 + j.
// ---------------------------------------------------------------------------
__global__ __launch_bounds__(256) void pack_kernel(const float* __restrict__ WF,
                                                   const float* __restrict__ WB,
                                                   uint* __restrict__ wregF,
                                                   uint* __restrict__ wregB,
                                                   uint* __restrict__ wldsF,
                                                   uint* __restrict__ wldsB) {
    int id = blockIdx.x * 256 + threadIdx.x;   // 0..262143
    const float* W = WF; uint* wr = wregF; uint* wl = wldsF;
    if (id >= 131072) { id -= 131072; W = WB; wr = wregB; wl = wldsB; }
    int m = id & 127;
    int g = id >> 7;
    int q = g >> 8, j = g & 255;
    float f0 = W[g * 256 + 2 * m];
    float f1 = W[g * 256 + 2 * m + 1];
    ushort u0 = __builtin_bit_cast(ushort, (_Float16)f0);
    ushort u1 = __builtin_bit_cast(ushort, (_Float16)f1);
    uint pk = (uint)u0 | ((uint)u1 << 16);
    if (m < 96) wr[(q * 96 + m) * 256 + j] = pk;
    else        wl[(m - 96) * 1024 + j * 4 + q] = pk;
}

// ---------------------------------------------------------------------------
// gemm_gx: gx_il[row][j*4+q] = emb[row] . Wih[q*256+j] + bias[q*256+j]
// (gate-interleaved output so lstm thread j reads one 8B dwordx2).
// Permuted B-row index: perm(col) = (col&3)*256 + (col>>2). fp32 compute,
// fp16 out. 64x64 tile, BK=16, 4x4/thread. Skips fully-masked row tiles.
// grid = (512, 16)
// ---------------------------------------------------------------------------
__global__ __launch_bounds__(256) void gemm_gx_kernel(const int* __restrict__ widx,
                                                      const int* __restrict__ lens,
                                                      const float* __restrict__ wvec,
                                                      const float* __restrict__ Wih,
                                                      const float* __restrict__ bias,
                                                      _Float16* __restrict__ gx) {
    int row0 = blockIdx.x * 64;
    int b = row0 >> 9;
    int t0 = row0 & 511;
    if (t0 >= lens[b]) return;
    int n0 = blockIdx.y * 64;

    __shared__ __align__(16) float As[16][68];
    __shared__ __align__(16) float Bs[16][68];
    __shared__ int aoff[64];

    int tid = threadIdx.x;
    if (tid < 64) aoff[tid] = widx[row0 + tid] << 8;
    __syncthreads();

    float acc[4][4] = {};
    int tn = tid & 15, tm = tid >> 4;

    for (int k0 = 0; k0 < 256; k0 += 16) {
#pragma unroll
        for (int p = 0; p < 4; ++p) {
            int lin = p * 256 + tid;
            int k = lin & 15, m = lin >> 4;
            int col = n0 + m;
            int perm = ((col & 3) << 8) + (col >> 2);   // gate-interleave
            As[k][m] = wvec[aoff[m] + k0 + k];
            Bs[k][m] = Wih[(perm << 8) + k0 + k];
        }
        __syncthreads();
#pragma unroll
        for (int k = 0; k < 16; ++k) {
            float4 av = *reinterpret_cast<const float4*>(&As[k][tm * 4]);
            float4 bv = *reinterpret_cast<const float4*>(&Bs[k][tn * 4]);
            float am[4] = {av.x, av.y, av.z, av.w};
            float bn[4] = {bv.x, bv.y, bv.z, bv.w};
#pragma unroll
            for (int i = 0; i < 4; ++i)
#pragma unroll
                for (int j = 0; j < 4; ++j) acc[i][j] = fmaf(am[i], bn[j], acc[i][j]);
        }
        __syncthreads();
    }

#pragma unroll
    for (int i = 0; i < 4; ++i) {
        int row = row0 + tm * 4 + i;
        ushort u[4];
#pragma unroll
        for (int j = 0; j < 4; ++j) {
            int col = n0 + tn * 4 + j;
            int perm = ((col & 3) << 8) + (col >> 2);
            u[j] = __builtin_bit_cast(ushort, (_Float16)(acc[i][j] + bias[perm]));
        }
        uint2 st;
        st.x = (uint)u[0] | ((uint)u[1] << 16);
        st.y = (uint)u[2] | ((uint)u[3] << 16);
        *reinterpret_cast<uint2*>(&gx[row * 1024 + n0 + tn * 4]) = st;
    }
}

// ---------------------------------------------------------------------------
// lstm_kernel: one block per (b, dir); 256 threads; thread j owns gates
// (i,f,g,o) of hidden j and h[j]. W_hh fp16 resident: 96 k-pairs/gate in
// VGPR+AGPR, 32 k-pairs in LDS. h broadcast via v_readlane (no LDS pipe):
// each wave keeps h as 128 fp16-pairs spread over its 64 lanes (2 uints/lane),
// refreshed by an 8B LDS read per step. gx read as one prefetched dwordx2.
// ---------------------------------------------------------------------------
__global__ __launch_bounds__(256, 1) void lstm_kernel(const _Float16* __restrict__ gx0,
                                                      const _Float16* __restrict__ gx1,
                                                      const uint* __restrict__ wreg0,
                                                      const uint* __restrict__ wreg1,
                                                      const uint* __restrict__ wlds0,
                                                      const uint* __restrict__ wlds1,
                                                      const int* __restrict__ lens,
                                                      float* __restrict__ feats) {
    int dir = blockIdx.x & 1;
    int b = blockIdx.x >> 1;
    const _Float16* gx = dir ? gx1 : gx0;
    const uint* wreg = dir ? wreg1 : wreg0;
    const uint* wlds = dir ? wlds1 : wlds0;
    int len = lens[b];
    int tid = threadIdx.x;
    int lane = tid & 63;

    __shared__ __align__(16) uint lw[32 * 1024];     // 128 KB W chunk
    __shared__ __align__(16) uint hpair[2][128];     // fp16-pair h, dbuf

    for (int i = tid; i < 32768; i += 256) lw[i] = wlds[i];

    uint wr0[96], wr1[96], wr2[96], wr3[96];
#pragma unroll
    for (int m = 0; m < 96; ++m) {
        wr0[m] = wreg[(m) * 256 + tid];
        wr1[m] = wreg[(96 + m) * 256 + tid];
        wr2[m] = wreg[(192 + m) * 256 + tid];
        wr3[m] = wreg[(288 + m) * 256 + tid];
    }
    __syncthreads();

    float c = 0.0f;
    uint r0 = 0, r1 = 0;           // this wave's h pairs: r0=pair[lane], r1=pair[64+lane]
    int pp = 0;

    // prefetch first gx (gate-interleaved: 4 halves at 4*tid)
    int t0i = dir ? (len - 1) : 0;
    uint2 g = *reinterpret_cast<const uint2*>(gx + ((size_t)((b << 9) + t0i) << 10) + (tid << 2));

    for (int tp = 0; tp < len; ++tp) {
        int t = dir ? (len - 1 - tp) : tp;
        // prefetch next step's gx (clamped; value unused on last step)
        int tnn = dir ? (len - 2 - tp) : (tp + 1);
        tnn = tnn < 0 ? 0 : (tnn >= len ? len - 1 : tnn);
        uint2 gnext = *reinterpret_cast<const uint2*>(gx + ((size_t)((b << 9) + tnn) << 10) + (tid << 2));

        half2_t u0 = __builtin_bit_cast(half2_t, g.x);
        half2_t u1 = __builtin_bit_cast(half2_t, g.y);
        float a0 = (float)u0.x;   // i
        float a1 = (float)u0.y;   // f
        float a2 = (float)u1.x;   // g
        float a3 = (float)u1.y;   // o

        // k-pairs 0..95: weights in VGPR/AGPR, h via readlane broadcast
#pragma unroll
        for (int m = 0; m < 96; ++m) {
            uint hp = (uint)__builtin_amdgcn_readlane((int)(m < 64 ? r0 : r1), m & 63);
            a0 = dot2f(wr0[m], hp, a0);
            a1 = dot2f(wr1[m], hp, a1);
            a2 = dot2f(wr2[m], hp, a2);
            a3 = dot2f(wr3[m], hp, a3);
        }
        // k-pairs 96..127: weights in LDS (uint4 per pair), h via readlane
#pragma unroll
        for (int i = 0; i < 32; ++i) {
            uint hp = (uint)__builtin_amdgcn_readlane((int)r1, 32 + i);
            const uint4 w = *reinterpret_cast<const uint4*>(&lw[i * 1024 + (tid << 2)]);
            a0 = dot2f(w.x, hp, a0);
            a1 = dot2f(w.y, hp, a1);
            a2 = dot2f(w.z, hp, a2);
            a3 = dot2f(w.w, hp, a3);
        }

        float ig = sigm(a0);
        float fg = sigm(a1);
        float gg = tanh_fast(a2);
        float og = sigm(a3);
        c = fg * c + ig * gg;
        float h = og * tanh_fast(c);

        reinterpret_cast<ushort*>(hpair[pp])[tid] = __builtin_bit_cast(ushort, (_Float16)h);
        feats[(size_t)(((b << 9) + t)) * 512 + (dir << 8) + tid] = h;
        __syncthreads();
        r0 = hpair[pp][lane];
        r1 = hpair[pp][64 + lane];
        pp ^= 1;
        g = gnext;
    }
}

// ---------------------------------------------------------------------------
// emis_kernel: emissions[b,t,k] = feats[b,t,:] . W_out[k,:] + b_out[k]
// ---------------------------------------------------------------------------
__global__ __launch_bounds__(64) void emis_kernel(const float* __restrict__ feats,
                                                  const float* __restrict__ Wout,
                                                  const float* __restrict__ bout,
                                                  const int* __restrict__ lens,
                                                  float* __restrict__ emis) {
    int r = blockIdx.x;
    int b = r >> 9, t = r & 511;
    if (t >= lens[b]) return;
    int lane = threadIdx.x;
    const float* fr = feats + (size_t)r * 512;
    float f[8];
#pragma unroll
    for (int i = 0; i < 8; ++i) f[i] = fr[i * 64 + lane];
#pragma unroll
    for (int k = 0; k < 9; ++k) {
        float p = 0.0f;
#pragma unroll
        for (int i = 0; i < 8; ++i) p = fmaf(f[i], Wout[k * 512 + i * 64 + lane], p);
#pragma unroll
        for (int off = 32; off; off >>= 1) p += __shfl_down(p, off);
        if (lane == 0) emis[r * 9 + k] = p + bout[k];
    }
}

// ---------------------------------------------------------------------------
// crf_kernel: alpha recursion + viterbi + backtrace + numerator + loss.
// ---------------------------------------------------------------------------
__global__ __launch_bounds__(64) void crf_kernel(const float* __restrict__ emis,
                                                 const int* __restrict__ lens,
                                                 const int* __restrict__ labels,
                                                 const float* __restrict__ start_trans,
                                                 const float* __restrict__ end_trans,
                                                 const float* __restrict__ trans,
                                                 float* __restrict__ out) {
    int b = blockIdx.x;
    int len = lens[b];
    int lane = threadIdx.x;
    __shared__ float alpha[9], vit[9];
    __shared__ unsigned char hist[512 * 9];
    const float* eb = emis + b * 512 * 9;
    const int* lb = labels + b * 512;

    float tr[9];
    if (lane < 9) {
#pragma unroll
        for (int i = 0; i < 9; ++i) tr[i] = trans[i * 9 + lane];
        float s0 = start_trans[lane] + eb[lane];
        alpha[lane] = s0;
        vit[lane] = s0;
    }
    __syncthreads();

    for (int t = 1; t < len; ++t) {
        float na = 0.0f, nv = 0.0f;
        if (lane < 9) {
            float e = eb[t * 9 + lane];
            float a[9];
#pragma unroll
            for (int i = 0; i < 9; ++i) a[i] = alpha[i] + tr[i];
            float m = a[0];
#pragma unroll
            for (int i = 1; i < 9; ++i) m = fmaxf(m, a[i]);
            float s = 0.0f;
#pragma unroll
            for (int i = 0; i < 9; ++i) s += __expf(a[i] - m);
            na = m + __logf(s) + e;
            float bv = vit[0] + tr[0];
            int bi = 0;
#pragma unroll
            for (int i = 1; i < 9; ++i) {
                float x = vit[i] + tr[i];
                if (x > bv) { bv = x; bi = i; }
            }
            nv = bv + e;
            hist[t * 9 + lane] = (unsigned char)bi;
        }
        __syncthreads();
        if (lane < 9) { alpha[lane] = na; vit[lane] = nv; }
        __syncthreads();
    }

    float part = 0.0f;
    for (int t = 1 + lane; t < len; t += 64) {
        int yp = lb[t - 1], y = lb[t];
        part += trans[yp * 9 + y] + eb[t * 9 + y];
    }
#pragma unroll
    for (int off = 32; off; off >>= 1) part += __shfl_down(part, off);

    if (lane == 0) {
        int y0 = lb[0];
        float num = start_trans[y0] + eb[y0] + part + end_trans[lb[len - 1]];
        float m = alpha[0] + end_trans[0];
        for (int j = 1; j < 9; ++j) m = fmaxf(m, alpha[j] + end_trans[j]);
        float s = 0.0f;
        for (int j = 0; j < 9; ++j) s += __expf(alpha[j] + end_trans[j] - m);
        float denom = m + __logf(s);
        atomicAdd(out, (denom - num) * (1.0f / 64.0f));

        float bm = vit[0] + end_trans[0];
        int cur = 0;
        for (int j = 1; j < 9; ++j) {
            float x = vit[j] + end_trans[j];
            if (x > bm) { bm = x; cur = j; }
        }
        float* preds = out + 1 + b * 512;
        preds[len - 1] = (float)cur;
        for (int t = len - 1; t >= 1; --t) {
            cur = hist[t * 9 + cur];
            preds[t - 1] = (float)cur;
        }
    }
}

// ---------------------------------------------------------------------------
extern "C" void kernel_launch(void* const* d_in, const int* in_sizes, int n_in,
                              void* d_out, int out_size, void* d_ws, size_t ws_size,
                              hipStream_t stream) {
    const int* widx = (const int*)d_in[0];
    const int* lens = (const int*)d_in[1];
    const int* labels = (const int*)d_in[2];
    const float* wvec = (const float*)d_in[3];
    const float* WihF = (const float*)d_in[4];
    const float* WhhF = (const float*)d_in[5];
    const float* bF = (const float*)d_in[6];
    const float* WihB = (const float*)d_in[7];
    const float* WhhB = (const float*)d_in[8];
    const float* bB = (const float*)d_in[9];
    const float* Wout = (const float*)d_in[10];
    const float* bout = (const float*)d_in[11];
    const float* trans9 = (const float*)d_in[14];
    const float* start_trans = (const float*)d_in[12];
    const float* end_trans = (const float*)d_in[13];
    float* out = (float*)d_out;
    char* ws = (char*)d_ws;

    // workspace layout (bytes) — total 136,445,952
    _Float16* gxF = (_Float16*)(ws);                        // 67,108,864 B
    _Float16* gxB = (_Float16*)(ws + 67108864);             // 67,108,864 B
    uint* wregF   = (uint*)(ws + 134217728);                // 393,216 B
    uint* wregB   = (uint*)(ws + 134610944);                // 393,216 B
    uint* wldsF   = (uint*)(ws + 135004160);                // 131,072 B
    uint* wldsB   = (uint*)(ws + 135135232);                // 131,072 B
    float* emis   = (float*)(ws + 135266304);               // 1,179,648 B
    (void)in_sizes; (void)n_in; (void)out_size; (void)ws_size;

    float* feats = out + 1 + 32768;   // feats output region (B,T,512) fp32

    zero_kernel<<<65665, 256, 0, stream>>>(out, lens);
    pack_kernel<<<1024, 256, 0, stream>>>(WhhF, WhhB, wregF, wregB, wldsF, wldsB);

    dim3 ggrid(512, 16);
    gemm_gx_kernel<<<ggrid, 256, 0, stream>>>(widx, lens, wvec, WihF, bF, gxF);
    gemm_gx_kernel<<<ggrid, 256, 0, stream>>>(widx, lens, wvec, WihB, bB, gxB);

    lstm_kernel<<<128, 256, 0, stream>>>(gxF, gxB, wregF, wregB, wldsF, wldsB, lens, feats);

    emis_kernel<<<32768, 64, 0, stream>>>(feats, Wout, bout, lens, emis);
    crf_kernel<<<64, 64, 0, stream>>>(emis, lens, labels, start_trans, end_trans, trans9, out);
}

// Round 4
// 1808.103 us; speedup vs baseline: 4.5511x; 1.2246x over previous
//
#include <hip/hip_runtime.h>
#include <hip/hip_bf16.h>
#include <math.h>

#ifndef __has_builtin
#define __has_builtin(x) 0
#endif

typedef unsigned int uint;
typedef unsigned short ushort;
typedef _Float16 half2_t __attribute__((ext_vector_type(2)));

// Problem constants: B=64, T=512, V=30000, E=256, H=256, K=9. 4H = 1024.

__device__ __forceinline__ float sigm(float x) {
    return __fdividef(1.0f, 1.0f + __expf(-x));
}
__device__ __forceinline__ float tanh_fast(float x) {
    // tanh(x) = 2*sigmoid(2x) - 1 ; inf-safe (1/(1+inf)=0)
    float sg = __fdividef(1.0f, 1.0f + __expf(-2.0f * x));
    return sg + sg - 1.0f;
}
__device__ __forceinline__ float dot2f(uint w, uint h, float acc) {
#if __has_builtin(__builtin_amdgcn_fdot2)
    return __builtin_amdgcn_fdot2(__builtin_bit_cast(half2_t, w),
                                  __builtin_bit_cast(half2_t, h), acc, false);
#else
    half2_t a = __builtin_bit_cast(half2_t, w);
    half2_t b = __builtin_bit_cast(half2_t, h);
    return acc + (float)a.x * (float)b.x + (float)a.y * (float)b.y;
#endif
}

// ---------------------------------------------------------------------------
// zero_kernel: zero loss, preds, and feats rows with t >= len (masked region).
// ---------------------------------------------------------------------------
__global__ __launch_bounds__(256) void zero_kernel(float* __restrict__ out,
                                                   const int* __restrict__ lens) {
    int bid = blockIdx.x;
    if (bid < 65536) {
        int g = bid * 256 + threadIdx.x;
        int row = g >> 9;
        int t = row & 511;
        int b = row >> 9;
        if (t >= lens[b]) out[32769 + g] = 0.0f;
    } else if (bid < 65536 + 128) {
        int p = (bid - 65536) * 256 + threadIdx.x;
        out[1 + p] = 0.0f;
    } else if (threadIdx.x == 0) {
        out[0] = 0.0f;
    }
}

// ---------------------------------------------------------------------------
// pack_kernel: W_hh (4H,H) fp32 -> fp16 k-pair-packed for the 512-thread
// lstm layout. Thread tl = 2j+s owns gates q=2s+x (x in {0,1}) of hidden j.
//   VGPR chunk (pairs m in [0,96)):  wreg[(m*2+x)*512 + tl]
//   LDS  chunk (pairs m in [96,128)): wlds[(m-96)*1024 + tl*2 + x]
// value = pack(W[q*256+j][2m], W[q*256+j][2m+1])
// grid = 1024 x 256 (first half fwd, second half bwd)
// ---------------------------------------------------------------------------
__global__ __launch_bounds__(256) void pack_kernel(const float* __restrict__ WF,
                                                   const float* __restrict__ WB,
                                                   uint* __restrict__ wregF,
                                                   uint* __restrict__ wregB,
                                                   uint* __restrict__ wldsF,
                                                   uint* __restrict__ wldsB) {
    int id = blockIdx.x * 256 + threadIdx.x;   // 0..262143
    const float* W = WF; uint* wr = wregF; uint* wl = wldsF;
    if (id >= 131072) { id -= 131072; W = WB; wr = wregB; wl = wldsB; }
    int tl = id & 511;          // lstm thread id
    int x  = (id >> 9) & 1;     // which of the thread's two gates
    int m  = id >> 10;          // k-pair 0..127
    int j = tl >> 1, s = tl & 1;
    int q = (s << 1) + x;       // gate row block
    float f0 = W[(((q << 8) + j) << 8) + 2 * m];
    float f1 = W[(((q << 8) + j) << 8) + 2 * m + 1];
    ushort u0 = __builtin_bit_cast(ushort, (_Float16)f0);
    ushort u1 = __builtin_bit_cast(ushort, (_Float16)f1);
    uint pk = (uint)u0 | ((uint)u1 << 16);
    if (m < 96) wr[((m << 1) + x) * 512 + tl];
    if (m < 96) wr[((m << 1) + x) * 512 + tl] = pk;
    else        wl[((m - 96) << 10) + (tl << 1) + x] = pk;
}

// ---------------------------------------------------------------------------
// gemm_gx: gx_il[row][col] = emb[row] . Wih[perm(col)] + bias[perm(col)],
// perm(col) = (col&3)*256 + (col>>2)  (gate-interleaved for the lstm).
// fp32 compute, fp16 out. 64x64 tile, BK=16, 4x4/thread. Skips masked tiles.
// grid = (512, 16)
// ---------------------------------------------------------------------------
__global__ __launch_bounds__(256) void gemm_gx_kernel(const int* __restrict__ widx,
                                                      const int* __restrict__ lens,
                                                      const float* __restrict__ wvec,
                                                      const float* __restrict__ Wih,
                                                      const float* __restrict__ bias,
                                                      _Float16* __restrict__ gx) {
    int row0 = blockIdx.x * 64;
    int b = row0 >> 9;
    int t0 = row0 & 511;
    if (t0 >= lens[b]) return;
    int n0 = blockIdx.y * 64;

    __shared__ __align__(16) float As[16][68];
    __shared__ __align__(16) float Bs[16][68];
    __shared__ int aoff[64];

    int tid = threadIdx.x;
    if (tid < 64) aoff[tid] = widx[row0 + tid] << 8;
    __syncthreads();

    float acc[4][4] = {};
    int tn = tid & 15, tm = tid >> 4;

    for (int k0 = 0; k0 < 256; k0 += 16) {
#pragma unroll
        for (int p = 0; p < 4; ++p) {
            int lin = p * 256 + tid;
            int k = lin & 15, m = lin >> 4;
            int col = n0 + m;
            int perm = ((col & 3) << 8) + (col >> 2);
            As[k][m] = wvec[aoff[m] + k0 + k];
            Bs[k][m] = Wih[(perm << 8) + k0 + k];
        }
        __syncthreads();
#pragma unroll
        for (int k = 0; k < 16; ++k) {
            float4 av = *reinterpret_cast<const float4*>(&As[k][tm * 4]);
            float4 bv = *reinterpret_cast<const float4*>(&Bs[k][tn * 4]);
            float am[4] = {av.x, av.y, av.z, av.w};
            float bn[4] = {bv.x, bv.y, bv.z, bv.w};
#pragma unroll
            for (int i = 0; i < 4; ++i)
#pragma unroll
                for (int j = 0; j < 4; ++j) acc[i][j] = fmaf(am[i], bn[j], acc[i][j]);
        }
        __syncthreads();
    }

#pragma unroll
    for (int i = 0; i < 4; ++i) {
        int row = row0 + tm * 4 + i;
        ushort u[4];
#pragma unroll
        for (int j = 0; j < 4; ++j) {
            int col = n0 + tn * 4 + j;
            int perm = ((col & 3) << 8) + (col >> 2);
            u[j] = __builtin_bit_cast(ushort, (_Float16)(acc[i][j] + bias[perm]));
        }
        uint2 st;
        st.x = (uint)u[0] | ((uint)u[1] << 16);
        st.y = (uint)u[2] | ((uint)u[3] << 16);
        *reinterpret_cast<uint2*>(&gx[row * 1024 + n0 + tn * 4]) = st;
    }
}

// ---------------------------------------------------------------------------
// lstm_kernel: one block per (b, dir); 512 threads. Thread 2j+s owns gate
// rows {2s, 2s+1} of hidden j (s=0: i,f; s=1: g,o). W_hh fp16 resident with
// NO spill: 2x96 k-pairs in VGPRs (192 regs) + 32 k-pairs in LDS (128 KB).
// h broadcast via v_readlane (wave holds h as 128 fp16-pairs in r0,r1).
// Gate halves exchanged with one __shfl_xor (adjacent lanes); c computed
// redundantly (bit-identically) in both lanes. One barrier per step.
// ---------------------------------------------------------------------------
__global__ __launch_bounds__(512, 2) void lstm_kernel(const _Float16* __restrict__ gx0,
                                                      const _Float16* __restrict__ gx1,
                                                      const uint* __restrict__ wreg0,
                                                      const uint* __restrict__ wreg1,
                                                      const uint* __restrict__ wlds0,
                                                      const uint* __restrict__ wlds1,
                                                      const int* __restrict__ lens,
                                                      float* __restrict__ feats) {
    int dir = blockIdx.x & 1;
    int b = blockIdx.x >> 1;
    const uint* gxu = reinterpret_cast<const uint*>(dir ? gx1 : gx0) + ((size_t)(b << 9) << 9);
    const uint* wreg = dir ? wreg1 : wreg0;
    const uint* wlds = dir ? wlds1 : wlds0;
    int len = lens[b];
    int tid = threadIdx.x;
    int lane = tid & 63;
    int sg = tid & 1;           // gate-pair selector

    __shared__ __align__(16) uint lw[32 * 1024];     // 128 KB LDS W chunk
    __shared__ __align__(16) uint hpair[2][128];     // fp16-pair h, dbuf

    for (int i = tid; i < 32768; i += 512) lw[i] = wlds[i];

    uint wA[96], wB[96];
#pragma unroll
    for (int m = 0; m < 96; ++m) {
        wA[m] = wreg[((m << 1) + 0) * 512 + tid];
        wB[m] = wreg[((m << 1) + 1) * 512 + tid];
    }
    __syncthreads();

    float c = 0.0f;
    uint r0 = 0, r1 = 0;        // wave-spread h pairs
    int pp = 0;

    int t0i = dir ? (len - 1) : 0;
    uint g = gxu[(t0i << 9) + tid];

    for (int tp = 0; tp < len; ++tp) {
        int t = dir ? (len - 1 - tp) : tp;
        int tnn = dir ? (len - 2 - tp) : (tp + 1);
        tnn = tnn < 0 ? 0 : (tnn >= len ? len - 1 : tnn);
        uint gnext = gxu[(tnn << 9) + tid];

        half2_t gv = __builtin_bit_cast(half2_t, g);
        float aA = (float)gv.x;   // gate 2s
        float aB = (float)gv.y;   // gate 2s+1

        // k-pairs 0..95: W in VGPRs, h broadcast via readlane
#pragma unroll
        for (int m = 0; m < 96; ++m) {
            uint hp = (uint)__builtin_amdgcn_readlane((int)(m < 64 ? r0 : r1), m & 63);
            aA = dot2f(wA[m], hp, aA);
            aB = dot2f(wB[m], hp, aB);
        }
        // k-pairs 96..127: W in LDS (uint2 per thread per pair)
#pragma unroll
        for (int i = 0; i < 32; ++i) {
            uint hp = (uint)__builtin_amdgcn_readlane((int)r1, 32 + i);
            uint2 w = reinterpret_cast<const uint2*>(lw)[(i << 9) + tid];
            aA = dot2f(w.x, hp, aA);
            aB = dot2f(w.y, hp, aB);
        }

        // s=0: pA=sigm(i), pB=sigm(f) ; s=1: pA=tanh(g), pB=sigm(o)
        float y = sg ? aA + aA : aA;
        float sgm = __fdividef(1.0f, 1.0f + __expf(-y));
        float pA = sg ? sgm + sgm - 1.0f : sgm;
        float pB = sigm(aB);

        float oA = __shfl_xor(pA, 1);
        float oB = __shfl_xor(pB, 1);
        float si = sg ? oA : pA;
        float sf = sg ? oB : pB;
        float tg = sg ? pA : oA;
        float so = sg ? pB : oB;

        c = sf * c + si * tg;                  // identical in both lanes
        float h = so * tanh_fast(c);

        if (!sg) {
            reinterpret_cast<ushort*>(hpair[pp])[tid >> 1] =
                __builtin_bit_cast(ushort, (_Float16)h);
            feats[(size_t)(((b << 9) + t)) * 512 + (dir << 8) + (tid >> 1)] = h;
        }
        __syncthreads();
        r0 = hpair[pp][lane];
        r1 = hpair[pp][64 + lane];
        pp ^= 1;
        g = gnext;
    }
}

// ---------------------------------------------------------------------------
// emis_kernel: emissions[b,t,k] = feats[b,t,:] . W_out[k,:] + b_out[k]
// ---------------------------------------------------------------------------
__global__ __launch_bounds__(64) void emis_kernel(const float* __restrict__ feats,
                                                  const float* __restrict__ Wout,
                                                  const float* __restrict__ bout,
                                                  const int* __restrict__ lens,
                                                  float* __restrict__ emis) {
    int r = blockIdx.x;
    int b = r >> 9, t = r & 511;
    if (t >= lens[b]) return;
    int lane = threadIdx.x;
    const float* fr = feats + (size_t)r * 512;
    float f[8];
#pragma unroll
    for (int i = 0; i < 8; ++i) f[i] = fr[i * 64 + lane];
#pragma unroll
    for (int k = 0; k < 9; ++k) {
        float p = 0.0f;
#pragma unroll
        for (int i = 0; i < 8; ++i) p = fmaf(f[i], Wout[k * 512 + i * 64 + lane], p);
#pragma unroll
        for (int off = 32; off; off >>= 1) p += __shfl_down(p, off);
        if (lane == 0) emis[r * 9 + k] = p + bout[k];
    }
}

// ---------------------------------------------------------------------------
// crf_kernel: alpha recursion + viterbi + backtrace + numerator + loss.
// ---------------------------------------------------------------------------
__global__ __launch_bounds__(64) void crf_kernel(const float* __restrict__ emis,
                                                 const int* __restrict__ lens,
                                                 const int* __restrict__ labels,
                                                 const float* __restrict__ start_trans,
                                                 const float* __restrict__ end_trans,
                                                 const float* __restrict__ trans,
                                                 float* __restrict__ out) {
    int b = blockIdx.x;
    int len = lens[b];
    int lane = threadIdx.x;
    __shared__ float alpha[9], vit[9];
    __shared__ unsigned char hist[512 * 9];
    const float* eb = emis + b * 512 * 9;
    const int* lb = labels + b * 512;

    float tr[9];
    if (lane < 9) {
#pragma unroll
        for (int i = 0; i < 9; ++i) tr[i] = trans[i * 9 + lane];
        float s0 = start_trans[lane] + eb[lane];
        alpha[lane] = s0;
        vit[lane] = s0;
    }
    __syncthreads();

    for (int t = 1; t < len; ++t) {
        float na = 0.0f, nv = 0.0f;
        if (lane < 9) {
            float e = eb[t * 9 + lane];
            float a[9];
#pragma unroll
            for (int i = 0; i < 9; ++i) a[i] = alpha[i] + tr[i];
            float m = a[0];
#pragma unroll
            for (int i = 1; i < 9; ++i) m = fmaxf(m, a[i]);
            float s = 0.0f;
#pragma unroll
            for (int i = 0; i < 9; ++i) s += __expf(a[i] - m);
            na = m + __logf(s) + e;
            float bv = vit[0] + tr[0];
            int bi = 0;
#pragma unroll
            for (int i = 1; i < 9; ++i) {
                float x = vit[i] + tr[i];
                if (x > bv) { bv = x; bi = i; }
            }
            nv = bv + e;
            hist[t * 9 + lane] = (unsigned char)bi;
        }
        __syncthreads();
        if (lane < 9) { alpha[lane] = na; vit[lane] = nv; }
        __syncthreads();
    }

    float part = 0.0f;
    for (int t = 1 + lane; t < len; t += 64) {
        int yp = lb[t - 1], y = lb[t];
        part += trans[yp * 9 + y] + eb[t * 9 + y];
    }
#pragma unroll
    for (int off = 32; off; off >>= 1) part += __shfl_down(part, off);

    if (lane == 0) {
        int y0 = lb[0];
        float num = start_trans[y0] + eb[y0] + part + end_trans[lb[len - 1]];
        float m = alpha[0] + end_trans[0];
        for (int j = 1; j < 9; ++j) m = fmaxf(m, alpha[j] + end_trans[j]);
        float s = 0.0f;
        for (int j = 0; j < 9; ++j) s += __expf(alpha[j] + end_trans[j] - m);
        float denom = m + __logf(s);
        atomicAdd(out, (denom - num) * (1.0f / 64.0f));

        float bm = vit[0] + end_trans[0];
        int cur = 0;
        for (int j = 1; j < 9; ++j) {
            float x = vit[j] + end_trans[j];
            if (x > bm) { bm = x; cur = j; }
        }
        float* preds = out + 1 + b * 512;
        preds[len - 1] = (float)cur;
        for (int t = len - 1; t >= 1; --t) {
            cur = hist[t * 9 + cur];
            preds[t - 1] = (float)cur;
        }
    }
}

// ---------------------------------------------------------------------------
extern "C" void kernel_launch(void* const* d_in, const int* in_sizes, int n_in,
                              void* d_out, int out_size, void* d_ws, size_t ws_size,
                              hipStream_t stream) {
    const int* widx = (const int*)d_in[0];
    const int* lens = (const int*)d_in[1];
    const int* labels = (const int*)d_in[2];
    const float* wvec = (const float*)d_in[3];
    const float* WihF = (const float*)d_in[4];
    const float* WhhF = (const float*)d_in[5];
    const float* bF = (const float*)d_in[6];
    const float* WihB = (const float*)d_in[7];
    const float* WhhB = (const float*)d_in[8];
    const float* bB = (const float*)d_in[9];
    const float* Wout = (const float*)d_in[10];
    const float* bout = (const float*)d_in[11];
    const float* start_trans = (const float*)d_in[12];
    const float* end_trans = (const float*)d_in[13];
    const float* trans9 = (const float*)d_in[14];
    float* out = (float*)d_out;
    char* ws = (char*)d_ws;

    // workspace layout (bytes) — total 136,445,952
    _Float16* gxF = (_Float16*)(ws);                        // 67,108,864 B
    _Float16* gxB = (_Float16*)(ws + 67108864);             // 67,108,864 B
    uint* wregF   = (uint*)(ws + 134217728);                // 393,216 B
    uint* wregB   = (uint*)(ws + 134610944);                // 393,216 B
    uint* wldsF   = (uint*)(ws + 135004160);                // 131,072 B
    uint* wldsB   = (uint*)(ws + 135135232);                // 131,072 B
    float* emis   = (float*)(ws + 135266304);               // 1,179,648 B
    (void)in_sizes; (void)n_in; (void)out_size; (void)ws_size;

    float* feats = out + 1 + 32768;   // feats output region (B,T,512) fp32

    zero_kernel<<<65665, 256, 0, stream>>>(out, lens);
    pack_kernel<<<1024, 256, 0, stream>>>(WhhF, WhhB, wregF, wregB, wldsF, wldsB);

    dim3 ggrid(512, 16);
    gemm_gx_kernel<<<ggrid, 256, 0, stream>>>(widx, lens, wvec, WihF, bF, gxF);
    gemm_gx_kernel<<<ggrid, 256, 0, stream>>>(widx, lens, wvec, WihB, bB, gxB);

    lstm_kernel<<<128, 512, 0, stream>>>(gxF, gxB, wregF, wregB, wldsF, wldsB, lens, feats);

    emis_kernel<<<32768, 64, 0, stream>>>(feats, Wout, bout, lens, emis);
    crf_kernel<<<64, 64, 0, stream>>>(emis, lens, labels, start_trans, end_trans, trans9, out);
}

// Round 5
// 1652.272 us; speedup vs baseline: 4.9803x; 1.0943x over previous
//
#include <hip/hip_runtime.h>
#include <hip/hip_bf16.h>
#include <math.h>

#ifndef __has_builtin
#define __has_builtin(x) 0
#endif

typedef unsigned int uint;
typedef unsigned short ushort;
typedef _Float16 half2_t __attribute__((ext_vector_type(2)));

// Problem constants: B=64, T=512, V=30000, E=256, H=256, K=9. 4H = 1024.
// LSTM resident-W split: 90 k-pairs/gate in VGPRs, 38 k-pairs in LDS.
#define PREG 90
#define PLDS 38   // pairs 90..127 ; 19 uint4 groups
#define WREG_UINTS (PREG * 2 * 512)        // 92160
#define WLDS_UINTS (PLDS * 512 * 2)        // 38912 (19 groups * 512 thr * uint4)

__device__ __forceinline__ float sigm(float x) {
    return __fdividef(1.0f, 1.0f + __expf(-x));
}
__device__ __forceinline__ float tanh_fast(float x) {
    float sg = __fdividef(1.0f, 1.0f + __expf(-2.0f * x));
    return sg + sg - 1.0f;
}
__device__ __forceinline__ float dot2f(uint w, uint h, float acc) {
#if __has_builtin(__builtin_amdgcn_fdot2)
    return __builtin_amdgcn_fdot2(__builtin_bit_cast(half2_t, w),
                                  __builtin_bit_cast(half2_t, h), acc, false);
#else
    half2_t a = __builtin_bit_cast(half2_t, w);
    half2_t b = __builtin_bit_cast(half2_t, h);
    return acc + (float)a.x * (float)b.x + (float)a.y * (float)b.y;
#endif
}
__device__ __forceinline__ uint packh2(float a, float b) {
    ushort u0 = __builtin_bit_cast(ushort, (_Float16)a);
    ushort u1 = __builtin_bit_cast(ushort, (_Float16)b);
    return (uint)u0 | ((uint)u1 << 16);
}

// ---------------------------------------------------------------------------
// zero_kernel: zero loss, preds, and feats rows with t >= len (masked region).
// ---------------------------------------------------------------------------
__global__ __launch_bounds__(256) void zero_kernel(float* __restrict__ out,
                                                   const int* __restrict__ lens) {
    int bid = blockIdx.x;
    if (bid < 65536) {
        int g = bid * 256 + threadIdx.x;
        int row = g >> 9;
        int t = row & 511;
        int b = row >> 9;
        if (t >= lens[b]) out[32769 + g] = 0.0f;
    } else if (bid < 65536 + 128) {
        int p = (bid - 65536) * 256 + threadIdx.x;
        out[1 + p] = 0.0f;
    } else if (threadIdx.x == 0) {
        out[0] = 0.0f;
    }
}

// ---------------------------------------------------------------------------
// pack_kernel: W_hh (4H,H) fp32 -> fp16 k-pair-packed. Thread tl=2j+s owns
// gates q=2s+x. VGPR chunk (m<90): wreg[(m*2+x)*512+tl]. LDS chunk
// (m=90..127): flat id2 = ((g*512+tl)*4 + c) with m=90+2g+(c>>1), x=c&1
// (uint4-per-thread-per-group layout for ds_read_b128).
// grid = 1024 x 256 (first 131072 ids fwd, rest bwd)
// ---------------------------------------------------------------------------
__global__ __launch_bounds__(256) void pack_kernel(const float* __restrict__ WF,
                                                   const float* __restrict__ WB,
                                                   uint* __restrict__ wregF,
                                                   uint* __restrict__ wregB,
                                                   uint* __restrict__ wldsF,
                                                   uint* __restrict__ wldsB) {
    int id = blockIdx.x * 256 + threadIdx.x;   // 0..262143
    const float* W = WF; uint* wr = wregF; uint* wl = wldsF;
    if (id >= 131072) { id -= 131072; W = WB; wr = wregB; wl = wldsB; }
    int m, x, tl, dst_lds = 0, id2 = 0;
    if (id < WREG_UINTS) {
        m = id >> 10;
        int r = id & 1023;
        x = r >> 9;
        tl = r & 511;
    } else {
        id2 = id - WREG_UINTS;            // 0..38911
        int c = id2 & 3;
        int u = id2 >> 2;
        tl = u & 511;
        int g = u >> 9;                   // 0..18
        m = PREG + 2 * g + (c >> 1);
        x = c & 1;
        dst_lds = 1;
    }
    int j = tl >> 1, s = tl & 1;
    int q = (s << 1) + x;
    const float* row = W + ((size_t)((q << 8) + j) << 8);
    uint pk = packh2(row[2 * m], row[2 * m + 1]);
    if (dst_lds) wl[id2] = pk;
    else         wr[((m << 1) + x) * 512 + tl] = pk;
}

// ---------------------------------------------------------------------------
// wih_pack_kernel: Wih (fp32, gate-major) -> fp16 k-pair packed, indexed by
// OUTPUT (interleaved) column: wih16[col*128 + p] = pack over perm(col) row.
// perm(col) = (col&3)*256 + (col>>2). grid = 1024 x 256.
// ---------------------------------------------------------------------------
__global__ __launch_bounds__(256) void wih_pack_kernel(const float* __restrict__ WihF,
                                                       const float* __restrict__ WihB,
                                                       uint* __restrict__ w16F,
                                                       uint* __restrict__ w16B) {
    int id = blockIdx.x * 256 + threadIdx.x;   // 0..262143
    const float* W = WihF; uint* dst = w16F;
    if (id >= 131072) { id -= 131072; W = WihB; dst = w16B; }
    int col = id >> 7;
    int p = id & 127;
    int perm = ((col & 3) << 8) + (col >> 2);
    const float* row = W + ((size_t)perm << 8);
    dst[(col << 7) + p] = packh2(row[2 * p], row[2 * p + 1]);
}

// ---------------------------------------------------------------------------
// gemm_gx: fp16-pair dot2 GEMM. gx_il[row][col] = emb[row].Wih[perm(col)] +
// bias[perm(col)]. A staged fp32->fp16 on the fly; B pre-packed (wih16).
// 64x64 tile, 32 k per iter (16 pairs), 4x4/thread. Skips masked tiles.
// grid = (512, 16)
// ---------------------------------------------------------------------------
__global__ __launch_bounds__(256) void gemm_gx_kernel(const int* __restrict__ widx,
                                                      const int* __restrict__ lens,
                                                      const float* __restrict__ wvec,
                                                      const uint* __restrict__ wih16,
                                                      const float* __restrict__ bias,
                                                      _Float16* __restrict__ gx) {
    int row0 = blockIdx.x * 64;
    int b = row0 >> 9;
    int t0 = row0 & 511;
    if (t0 >= lens[b]) return;
    int n0 = blockIdx.y * 64;

    __shared__ __align__(16) uint As[16][68];   // [k-pair][row]
    __shared__ __align__(16) uint Bs[16][68];   // [k-pair][col]
    __shared__ int aoff[64];

    int tid = threadIdx.x;
    if (tid < 64) aoff[tid] = widx[row0 + tid] << 8;
    __syncthreads();

    float acc[4][4] = {};
    int tn = tid & 15, tm = tid >> 4;

    for (int k0p = 0; k0p < 128; k0p += 16) {   // 16 k-pairs = 32 k per iter
#pragma unroll
        for (int p = 0; p < 4; ++p) {
            int lin = p * 256 + tid;
            int kp = lin & 15, m = lin >> 4;
            const float2 av = *reinterpret_cast<const float2*>(
                &wvec[aoff[m] + ((k0p + kp) << 1)]);
            As[kp][m] = packh2(av.x, av.y);
            Bs[kp][m] = wih16[((n0 + m) << 7) + k0p + kp];
        }
        __syncthreads();
#pragma unroll
        for (int kp = 0; kp < 16; ++kp) {
            uint4 a4 = *reinterpret_cast<const uint4*>(&As[kp][tm * 4]);
            uint4 b4 = *reinterpret_cast<const uint4*>(&Bs[kp][tn * 4]);
            uint am[4] = {a4.x, a4.y, a4.z, a4.w};
            uint bn[4] = {b4.x, b4.y, b4.z, b4.w};
#pragma unroll
            for (int i = 0; i < 4; ++i)
#pragma unroll
                for (int j = 0; j < 4; ++j) acc[i][j] = dot2f(am[i], bn[j], acc[i][j]);
        }
        __syncthreads();
    }

#pragma unroll
    for (int i = 0; i < 4; ++i) {
        int row = row0 + tm * 4 + i;
        ushort u[4];
#pragma unroll
        for (int j = 0; j < 4; ++j) {
            int col = n0 + tn * 4 + j;
            int perm = ((col & 3) << 8) + (col >> 2);
            u[j] = __builtin_bit_cast(ushort, (_Float16)(acc[i][j] + bias[perm]));
        }
        uint2 st;
        st.x = (uint)u[0] | ((uint)u[1] << 16);
        st.y = (uint)u[2] | ((uint)u[3] << 16);
        *reinterpret_cast<uint2*>(&gx[row * 1024 + n0 + tn * 4]) = st;
    }
}

// ---------------------------------------------------------------------------
// lstm_kernel: one block per (b, dir); 512 threads. Thread 2j+s owns gate
// rows {2s, 2s+1} of hidden j. W_hh fp16 resident: 2x90 k-pairs in VGPRs
// (180 regs, ~45 reg headroom -> no spill) + 38 k-pairs in LDS (152 KB,
// ds_read_b128). h broadcast via v_readlane; gate halves exchanged with one
// __shfl_xor; c redundantly computed in both lanes. One barrier per step.
// ---------------------------------------------------------------------------
__global__ __launch_bounds__(512, 2) void lstm_kernel(const _Float16* __restrict__ gx0,
                                                      const _Float16* __restrict__ gx1,
                                                      const uint* __restrict__ wreg0,
                                                      const uint* __restrict__ wreg1,
                                                      const uint* __restrict__ wlds0,
                                                      const uint* __restrict__ wlds1,
                                                      const int* __restrict__ lens,
                                                      float* __restrict__ feats) {
    int dir = blockIdx.x & 1;
    int b = blockIdx.x >> 1;
    const uint* gxu = reinterpret_cast<const uint*>(dir ? gx1 : gx0) + ((size_t)(b << 9) << 9);
    const uint* wreg = dir ? wreg1 : wreg0;
    const uint* wlds = dir ? wlds1 : wlds0;
    int len = lens[b];
    int tid = threadIdx.x;
    int lane = tid & 63;
    int sg = tid & 1;

    __shared__ __align__(16) uint lw[WLDS_UINTS];    // 152 KB LDS W chunk
    __shared__ __align__(16) uint hpair[2][128];     // fp16-pair h, dbuf

    for (int i = tid; i < WLDS_UINTS; i += 512) lw[i] = wlds[i];

    uint wA[PREG], wB[PREG];
#pragma unroll
    for (int m = 0; m < PREG; ++m) {
        wA[m] = wreg[((m << 1) + 0) * 512 + tid];
        wB[m] = wreg[((m << 1) + 1) * 512 + tid];
    }
    __syncthreads();

    float c = 0.0f;
    uint r0 = 0, r1 = 0;
    int pp = 0;

    int t0i = dir ? (len - 1) : 0;
    uint g = gxu[(t0i << 9) + tid];

    for (int tp = 0; tp < len; ++tp) {
        int t = dir ? (len - 1 - tp) : tp;
        int tnn = dir ? (len - 2 - tp) : (tp + 1);
        tnn = tnn < 0 ? 0 : (tnn >= len ? len - 1 : tnn);
        uint gnext = gxu[(tnn << 9) + tid];

        half2_t gv = __builtin_bit_cast(half2_t, g);
        float aA = (float)gv.x;
        float aB = (float)gv.y;

        // k-pairs 0..89: W in VGPRs, h via readlane
#pragma unroll
        for (int m = 0; m < PREG; ++m) {
            uint hp = (uint)__builtin_amdgcn_readlane((int)(m < 64 ? r0 : r1), m & 63);
            aA = dot2f(wA[m], hp, aA);
            aB = dot2f(wB[m], hp, aB);
        }
        // k-pairs 90..127: W in LDS, uint4 covers 2 pairs x 2 gates
#pragma unroll
        for (int i = 0; i < 19; ++i) {
            uint4 w4 = reinterpret_cast<const uint4*>(lw)[(i << 9) + tid];
            uint hp0 = (uint)__builtin_amdgcn_readlane((int)r1, 26 + 2 * i);
            uint hp1 = (uint)__builtin_amdgcn_readlane((int)r1, 27 + 2 * i);
            aA = dot2f(w4.x, hp0, aA);
            aB = dot2f(w4.y, hp0, aB);
            aA = dot2f(w4.z, hp1, aA);
            aB = dot2f(w4.w, hp1, aB);
        }

        // s=0: pA=sigm(i), pB=sigm(f) ; s=1: pA=tanh(g), pB=sigm(o)
        float y = sg ? aA + aA : aA;
        float sgm = __fdividef(1.0f, 1.0f + __expf(-y));
        float pA = sg ? sgm + sgm - 1.0f : sgm;
        float pB = sigm(aB);

        float oA = __shfl_xor(pA, 1);
        float oB = __shfl_xor(pB, 1);
        float si = sg ? oA : pA;
        float sf = sg ? oB : pB;
        float tg = sg ? pA : oA;
        float so = sg ? pB : oB;

        c = sf * c + si * tg;
        float h = so * tanh_fast(c);

        if (!sg) {
            reinterpret_cast<ushort*>(hpair[pp])[tid >> 1] =
                __builtin_bit_cast(ushort, (_Float16)h);
            feats[(size_t)(((b << 9) + t)) * 512 + (dir << 8) + (tid >> 1)] = h;
        }
        __syncthreads();
        r0 = hpair[pp][lane];
        r1 = hpair[pp][64 + lane];
        pp ^= 1;
        g = gnext;
    }
}

// ---------------------------------------------------------------------------
// emis_kernel: emissions[b,t,k] = feats[b,t,:] . W_out[k,:] + b_out[k]
// ---------------------------------------------------------------------------
__global__ __launch_bounds__(64) void emis_kernel(const float* __restrict__ feats,
                                                  const float* __restrict__ Wout,
                                                  const float* __restrict__ bout,
                                                  const int* __restrict__ lens,
                                                  float* __restrict__ emis) {
    int r = blockIdx.x;
    int b = r >> 9, t = r & 511;
    if (t >= lens[b]) return;
    int lane = threadIdx.x;
    const float* fr = feats + (size_t)r * 512;
    float f[8];
#pragma unroll
    for (int i = 0; i < 8; ++i) f[i] = fr[i * 64 + lane];
#pragma unroll
    for (int k = 0; k < 9; ++k) {
        float p = 0.0f;
#pragma unroll
        for (int i = 0; i < 8; ++i) p = fmaf(f[i], Wout[k * 512 + i * 64 + lane], p);
#pragma unroll
        for (int off = 32; off; off >>= 1) p += __shfl_down(p, off);
        if (lane == 0) emis[r * 9 + k] = p + bout[k];
    }
}

// ---------------------------------------------------------------------------
// crf_kernel: alpha recursion + viterbi + backtrace + numerator + loss.
// ---------------------------------------------------------------------------
__global__ __launch_bounds__(64) void crf_kernel(const float* __restrict__ emis,
                                                 const int* __restrict__ lens,
                                                 const int* __restrict__ labels,
                                                 const float* __restrict__ start_trans,
                                                 const float* __restrict__ end_trans,
                                                 const float* __restrict__ trans,
                                                 float* __restrict__ out) {
    int b = blockIdx.x;
    int len = lens[b];
    int lane = threadIdx.x;
    __shared__ float alpha[9], vit[9];
    __shared__ unsigned char hist[512 * 9];
    const float* eb = emis + b * 512 * 9;
    const int* lb = labels + b * 512;

    float tr[9];
    if (lane < 9) {
#pragma unroll
        for (int i = 0; i < 9; ++i) tr[i] = trans[i * 9 + lane];
        float s0 = start_trans[lane] + eb[lane];
        alpha[lane] = s0;
        vit[lane] = s0;
    }
    __syncthreads();

    for (int t = 1; t < len; ++t) {
        float na = 0.0f, nv = 0.0f;
        if (lane < 9) {
            float e = eb[t * 9 + lane];
            float a[9];
#pragma unroll
            for (int i = 0; i < 9; ++i) a[i] = alpha[i] + tr[i];
            float m = a[0];
#pragma unroll
            for (int i = 1; i < 9; ++i) m = fmaxf(m, a[i]);
            float s = 0.0f;
#pragma unroll
            for (int i = 0; i < 9; ++i) s += __expf(a[i] - m);
            na = m + __logf(s) + e;
            float bv = vit[0] + tr[0];
            int bi = 0;
#pragma unroll
            for (int i = 1; i < 9; ++i) {
                float x = vit[i] + tr[i];
                if (x > bv) { bv = x; bi = i; }
            }
            nv = bv + e;
            hist[t * 9 + lane] = (unsigned char)bi;
        }
        __syncthreads();
        if (lane < 9) { alpha[lane] = na; vit[lane] = nv; }
        __syncthreads();
    }

    float part = 0.0f;
    for (int t = 1 + lane; t < len; t += 64) {
        int yp = lb[t - 1], y = lb[t];
        part += trans[yp * 9 + y] + eb[t * 9 + y];
    }
#pragma unroll
    for (int off = 32; off; off >>= 1) part += __shfl_down(part, off);

    if (lane == 0) {
        int y0 = lb[0];
        float num = start_trans[y0] + eb[y0] + part + end_trans[lb[len - 1]];
        float m = alpha[0] + end_trans[0];
        for (int j = 1; j < 9; ++j) m = fmaxf(m, alpha[j] + end_trans[j]);
        float s = 0.0f;
        for (int j = 0; j < 9; ++j) s += __expf(alpha[j] + end_trans[j] - m);
        float denom = m + __logf(s);
        atomicAdd(out, (denom - num) * (1.0f / 64.0f));

        float bm = vit[0] + end_trans[0];
        int cur = 0;
        for (int j = 1; j < 9; ++j) {
            float x = vit[j] + end_trans[j];
            if (x > bm) { bm = x; cur = j; }
        }
        float* preds = out + 1 + b * 512;
        preds[len - 1] = (float)cur;
        for (int t = len - 1; t >= 1; --t) {
            cur = hist[t * 9 + cur];
            preds[t - 1] = (float)cur;
        }
    }
}

// ---------------------------------------------------------------------------
extern "C" void kernel_launch(void* const* d_in, const int* in_sizes, int n_in,
                              void* d_out, int out_size, void* d_ws, size_t ws_size,
                              hipStream_t stream) {
    const int* widx = (const int*)d_in[0];
    const int* lens = (const int*)d_in[1];
    const int* labels = (const int*)d_in[2];
    const float* wvec = (const float*)d_in[3];
    const float* WihF = (const float*)d_in[4];
    const float* WhhF = (const float*)d_in[5];
    const float* bF = (const float*)d_in[6];
    const float* WihB = (const float*)d_in[7];
    const float* WhhB = (const float*)d_in[8];
    const float* bB = (const float*)d_in[9];
    const float* Wout = (const float*)d_in[10];
    const float* bout = (const float*)d_in[11];
    const float* start_trans = (const float*)d_in[12];
    const float* end_trans = (const float*)d_in[13];
    const float* trans9 = (const float*)d_in[14];
    float* out = (float*)d_out;
    char* ws = (char*)d_ws;

    // workspace layout (bytes) — total 136,445,952 (<= proven 137,486,336)
    _Float16* gxF = (_Float16*)(ws);                        // 67,108,864
    _Float16* gxB = (_Float16*)(ws + 67108864);             // 67,108,864
    uint* wregF   = (uint*)(ws + 134217728);                // 368,640
    uint* wregB   = (uint*)(ws + 134586368);                // 368,640
    uint* wldsF   = (uint*)(ws + 134955008);                // 155,648
    uint* wldsB   = (uint*)(ws + 135110656);                // 155,648
    // wih16F/B live only during gemm; emis written after lstm -> safe alias
    uint* wih16F  = (uint*)(ws + 135266304);                // 524,288
    uint* wih16B  = (uint*)(ws + 135790592);                // 524,288
    float* emis   = (float*)(ws + 135266304);               // 1,179,648 (alias)
    (void)in_sizes; (void)n_in; (void)out_size; (void)ws_size;

    float* feats = out + 1 + 32768;   // feats output region (B,T,512) fp32

    zero_kernel<<<65665, 256, 0, stream>>>(out, lens);
    pack_kernel<<<1024, 256, 0, stream>>>(WhhF, WhhB, wregF, wregB, wldsF, wldsB);
    wih_pack_kernel<<<1024, 256, 0, stream>>>(WihF, WihB, wih16F, wih16B);

    dim3 ggrid(512, 16);
    gemm_gx_kernel<<<ggrid, 256, 0, stream>>>(widx, lens, wvec, wih16F, bF, gxF);
    gemm_gx_kernel<<<ggrid, 256, 0, stream>>>(widx, lens, wvec, wih16B, bB, gxB);

    lstm_kernel<<<128, 512, 0, stream>>>(gxF, gxB, wregF, wregB, wldsF, wldsB, lens, feats);

    emis_kernel<<<32768, 64, 0, stream>>>(feats, Wout, bout, lens, emis);
    crf_kernel<<<64, 64, 0, stream>>>(emis, lens, labels, start_trans, end_trans, trans9, out);
}

// Round 6
// 1651.765 us; speedup vs baseline: 4.9819x; 1.0003x over previous
//
#include <hip/hip_runtime.h>
#include <hip/hip_bf16.h>
#include <math.h>

#ifndef __has_builtin
#define __has_builtin(x) 0
#endif

typedef unsigned int uint;
typedef unsigned short ushort;
typedef _Float16 half2_t __attribute__((ext_vector_type(2)));

// Problem constants: B=64, T=512, V=30000, E=256, H=256, K=9. 4H = 1024.
// LSTM resident-W split: 96 k-pairs/gate as NAMED SCALARS (192 VGPRs),
// 32 k-pairs in LDS (128 KB). Scalars (not arrays!) cannot become allocas,
// so no scratch spill — this was the r2-r5 failure mode (VGPR_Count 112-204
// with arrays: allocas stayed in scratch, re-streamed every step).
#define PREG 96
#define WREG_UINTS (PREG * 2 * 512)        // 98304
#define WLDS_UINTS (16 * 512 * 4)          // 32768 (16 uint4-groups)

__device__ __forceinline__ float sigm(float x) {
    return __fdividef(1.0f, 1.0f + __expf(-x));
}
__device__ __forceinline__ float tanh_fast(float x) {
    float sg = __fdividef(1.0f, 1.0f + __expf(-2.0f * x));
    return sg + sg - 1.0f;
}
__device__ __forceinline__ float dot2f(uint w, uint h, float acc) {
#if __has_builtin(__builtin_amdgcn_fdot2)
    return __builtin_amdgcn_fdot2(__builtin_bit_cast(half2_t, w),
                                  __builtin_bit_cast(half2_t, h), acc, false);
#else
    half2_t a = __builtin_bit_cast(half2_t, w);
    half2_t b = __builtin_bit_cast(half2_t, h);
    return acc + (float)a.x * (float)b.x + (float)a.y * (float)b.y;
#endif
}
__device__ __forceinline__ uint packh2(float a, float b) {
    ushort u0 = __builtin_bit_cast(ushort, (_Float16)a);
    ushort u1 = __builtin_bit_cast(ushort, (_Float16)b);
    return (uint)u0 | ((uint)u1 << 16);
}

// ---- preprocessor repetition ------------------------------------------------
#define R96(X) \
  X(0) X(1) X(2) X(3) X(4) X(5) X(6) X(7) \
  X(8) X(9) X(10) X(11) X(12) X(13) X(14) X(15) \
  X(16) X(17) X(18) X(19) X(20) X(21) X(22) X(23) \
  X(24) X(25) X(26) X(27) X(28) X(29) X(30) X(31) \
  X(32) X(33) X(34) X(35) X(36) X(37) X(38) X(39) \
  X(40) X(41) X(42) X(43) X(44) X(45) X(46) X(47) \
  X(48) X(49) X(50) X(51) X(52) X(53) X(54) X(55) \
  X(56) X(57) X(58) X(59) X(60) X(61) X(62) X(63) \
  X(64) X(65) X(66) X(67) X(68) X(69) X(70) X(71) \
  X(72) X(73) X(74) X(75) X(76) X(77) X(78) X(79) \
  X(80) X(81) X(82) X(83) X(84) X(85) X(86) X(87) \
  X(88) X(89) X(90) X(91) X(92) X(93) X(94) X(95)

#define R16(X) \
  X(0) X(1) X(2) X(3) X(4) X(5) X(6) X(7) \
  X(8) X(9) X(10) X(11) X(12) X(13) X(14) X(15)

#define WDECL(m) uint wA##m, wB##m;
#define WLOAD(m) wA##m = wreg[(2 * (m)) * 512 + tid]; \
                 wB##m = wreg[(2 * (m) + 1) * 512 + tid];
#define WSTEP(m) { \
    uint hp = (uint)__builtin_amdgcn_readlane((int)((m) < 64 ? r0 : r1), (m) & 63); \
    aA = dot2f(wA##m, hp, aA); \
    aB = dot2f(wB##m, hp, aB); }
#define LSTEP(i) { \
    uint4 w4 = reinterpret_cast<const uint4*>(lw)[((i) << 9) + tid]; \
    uint hp0 = (uint)__builtin_amdgcn_readlane((int)r1, 32 + 2 * (i)); \
    uint hp1 = (uint)__builtin_amdgcn_readlane((int)r1, 33 + 2 * (i)); \
    aA = dot2f(w4.x, hp0, aA); \
    aB = dot2f(w4.y, hp0, aB); \
    aA = dot2f(w4.z, hp1, aA); \
    aB = dot2f(w4.w, hp1, aB); }

// ---------------------------------------------------------------------------
// zero_kernel: zero loss, preds, and feats rows with t >= len (masked region).
// ---------------------------------------------------------------------------
__global__ __launch_bounds__(256) void zero_kernel(float* __restrict__ out,
                                                   const int* __restrict__ lens) {
    int bid = blockIdx.x;
    if (bid < 65536) {
        int g = bid * 256 + threadIdx.x;
        int row = g >> 9;
        int t = row & 511;
        int b = row >> 9;
        if (t >= lens[b]) out[32769 + g] = 0.0f;
    } else if (bid < 65536 + 128) {
        int p = (bid - 65536) * 256 + threadIdx.x;
        out[1 + p] = 0.0f;
    } else if (threadIdx.x == 0) {
        out[0] = 0.0f;
    }
}

// ---------------------------------------------------------------------------
// pack_kernel: W_hh (4H,H) fp32 -> fp16 k-pair-packed. Thread tl=2j+s owns
// gates q=2s+x. Scalar chunk (m<96): wreg[(m*2+x)*512+tl]. LDS chunk
// (m=96..127): flat id2 = ((g*512+tl)*4 + c), m=96+2g+(c>>1), x=c&1.
// Per-direction ids: 98304 + 32768 = 131072. grid = 1024 x 256.
// ---------------------------------------------------------------------------
__global__ __launch_bounds__(256) void pack_kernel(const float* __restrict__ WF,
                                                   const float* __restrict__ WB,
                                                   uint* __restrict__ wregF,
                                                   uint* __restrict__ wregB,
                                                   uint* __restrict__ wldsF,
                                                   uint* __restrict__ wldsB) {
    int id = blockIdx.x * 256 + threadIdx.x;   // 0..262143
    const float* W = WF; uint* wr = wregF; uint* wl = wldsF;
    if (id >= 131072) { id -= 131072; W = WB; wr = wregB; wl = wldsB; }
    int m, x, tl, dst_lds = 0, id2 = 0;
    if (id < WREG_UINTS) {
        m = id >> 10;
        int r = id & 1023;
        x = r >> 9;
        tl = r & 511;
    } else {
        id2 = id - WREG_UINTS;            // 0..32767
        int c = id2 & 3;
        int u = id2 >> 2;
        tl = u & 511;
        int g = u >> 9;                   // 0..15
        m = PREG + 2 * g + (c >> 1);
        x = c & 1;
        dst_lds = 1;
    }
    int j = tl >> 1, s = tl & 1;
    int q = (s << 1) + x;
    const float* row = W + ((size_t)((q << 8) + j) << 8);
    uint pk = packh2(row[2 * m], row[2 * m + 1]);
    if (dst_lds) wl[id2] = pk;
    else         wr[((m << 1) + x) * 512 + tl] = pk;
}

// ---------------------------------------------------------------------------
// wih_pack_kernel: Wih fp32 -> fp16 k-pair packed, indexed by interleaved
// output column: wih16[col*128 + p], perm(col) = (col&3)*256 + (col>>2).
// ---------------------------------------------------------------------------
__global__ __launch_bounds__(256) void wih_pack_kernel(const float* __restrict__ WihF,
                                                       const float* __restrict__ WihB,
                                                       uint* __restrict__ w16F,
                                                       uint* __restrict__ w16B) {
    int id = blockIdx.x * 256 + threadIdx.x;   // 0..262143
    const float* W = WihF; uint* dst = w16F;
    if (id >= 131072) { id -= 131072; W = WihB; dst = w16B; }
    int col = id >> 7;
    int p = id & 127;
    int perm = ((col & 3) << 8) + (col >> 2);
    const float* row = W + ((size_t)perm << 8);
    dst[(col << 7) + p] = packh2(row[2 * p], row[2 * p + 1]);
}

// ---------------------------------------------------------------------------
// gemm_gx: fp16-pair dot2 GEMM. gx_il[row][col] = emb[row].Wih[perm(col)] +
// bias[perm(col)]. 64x64 tile, 32 k per iter, 4x4/thread. Skips masked tiles.
// grid = (512, 16)
// ---------------------------------------------------------------------------
__global__ __launch_bounds__(256) void gemm_gx_kernel(const int* __restrict__ widx,
                                                      const int* __restrict__ lens,
                                                      const float* __restrict__ wvec,
                                                      const uint* __restrict__ wih16,
                                                      const float* __restrict__ bias,
                                                      _Float16* __restrict__ gx) {
    int row0 = blockIdx.x * 64;
    int b = row0 >> 9;
    int t0 = row0 & 511;
    if (t0 >= lens[b]) return;
    int n0 = blockIdx.y * 64;

    __shared__ __align__(16) uint As[16][68];
    __shared__ __align__(16) uint Bs[16][68];
    __shared__ int aoff[64];

    int tid = threadIdx.x;
    if (tid < 64) aoff[tid] = widx[row0 + tid] << 8;
    __syncthreads();

    float acc[4][4] = {};
    int tn = tid & 15, tm = tid >> 4;

    for (int k0p = 0; k0p < 128; k0p += 16) {
#pragma unroll
        for (int p = 0; p < 4; ++p) {
            int lin = p * 256 + tid;
            int kp = lin & 15, m = lin >> 4;
            const float2 av = *reinterpret_cast<const float2*>(
                &wvec[aoff[m] + ((k0p + kp) << 1)]);
            As[kp][m] = packh2(av.x, av.y);
            Bs[kp][m] = wih16[((n0 + m) << 7) + k0p + kp];
        }
        __syncthreads();
#pragma unroll
        for (int kp = 0; kp < 16; ++kp) {
            uint4 a4 = *reinterpret_cast<const uint4*>(&As[kp][tm * 4]);
            uint4 b4 = *reinterpret_cast<const uint4*>(&Bs[kp][tn * 4]);
            uint am[4] = {a4.x, a4.y, a4.z, a4.w};
            uint bn[4] = {b4.x, b4.y, b4.z, b4.w};
#pragma unroll
            for (int i = 0; i < 4; ++i)
#pragma unroll
                for (int j = 0; j < 4; ++j) acc[i][j] = dot2f(am[i], bn[j], acc[i][j]);
        }
        __syncthreads();
    }

#pragma unroll
    for (int i = 0; i < 4; ++i) {
        int row = row0 + tm * 4 + i;
        ushort u[4];
#pragma unroll
        for (int j = 0; j < 4; ++j) {
            int col = n0 + tn * 4 + j;
            int perm = ((col & 3) << 8) + (col >> 2);
            u[j] = __builtin_bit_cast(ushort, (_Float16)(acc[i][j] + bias[perm]));
        }
        uint2 st;
        st.x = (uint)u[0] | ((uint)u[1] << 16);
        st.y = (uint)u[2] | ((uint)u[3] << 16);
        *reinterpret_cast<uint2*>(&gx[row * 1024 + n0 + tn * 4]) = st;
    }
}

// ---------------------------------------------------------------------------
// lstm_kernel: one block per (b, dir); 512 threads. Thread 2j+s owns gate
// rows {2s, 2s+1} of hidden j. W_hh fp16 resident: 96 k-pairs/gate as 192
// NAMED SCALAR uints (guaranteed SSA -> VGPRs, no alloca/scratch possible)
// + 32 k-pairs in LDS (128 KB, ds_read_b128). h broadcast via v_readlane;
// gate halves exchanged via __shfl_xor; c redundant in both lanes.
// ---------------------------------------------------------------------------
__global__ __launch_bounds__(512, 2) void lstm_kernel(const _Float16* __restrict__ gx0,
                                                      const _Float16* __restrict__ gx1,
                                                      const uint* __restrict__ wreg0,
                                                      const uint* __restrict__ wreg1,
                                                      const uint* __restrict__ wlds0,
                                                      const uint* __restrict__ wlds1,
                                                      const int* __restrict__ lens,
                                                      float* __restrict__ feats) {
    int dir = blockIdx.x & 1;
    int b = blockIdx.x >> 1;
    const uint* gxu = reinterpret_cast<const uint*>(dir ? gx1 : gx0) + ((size_t)(b << 9) << 9);
    const uint* wreg = dir ? wreg1 : wreg0;
    const uint* wlds = dir ? wlds1 : wlds0;
    int len = lens[b];
    int tid = threadIdx.x;
    int lane = tid & 63;
    int sg = tid & 1;

    __shared__ __align__(16) uint lw[WLDS_UINTS];    // 128 KB LDS W chunk
    __shared__ __align__(16) uint hpair[2][128];     // fp16-pair h, dbuf

    for (int i = tid; i < WLDS_UINTS; i += 512) lw[i] = wlds[i];

    R96(WDECL)            // uint wA0..wA95, wB0..wB95 — named scalars
    R96(WLOAD)
    __syncthreads();

    float c = 0.0f;
    uint r0 = 0, r1 = 0;
    int pp = 0;

    int t0i = dir ? (len - 1) : 0;
    uint g = gxu[(t0i << 9) + tid];

    for (int tp = 0; tp < len; ++tp) {
        int t = dir ? (len - 1 - tp) : tp;
        int tnn = dir ? (len - 2 - tp) : (tp + 1);
        tnn = tnn < 0 ? 0 : (tnn >= len ? len - 1 : tnn);
        uint gnext = gxu[(tnn << 9) + tid];

        half2_t gv = __builtin_bit_cast(half2_t, g);
        float aA = (float)gv.x;
        float aB = (float)gv.y;

        R96(WSTEP)        // k-pairs 0..95: W in VGPRs, h via readlane
        R16(LSTEP)        // k-pairs 96..127: W in LDS

        // s=0: pA=sigm(i), pB=sigm(f) ; s=1: pA=tanh(g), pB=sigm(o)
        float y = sg ? aA + aA : aA;
        float sgm = __fdividef(1.0f, 1.0f + __expf(-y));
        float pA = sg ? sgm + sgm - 1.0f : sgm;
        float pB = sigm(aB);

        float oA = __shfl_xor(pA, 1);
        float oB = __shfl_xor(pB, 1);
        float si = sg ? oA : pA;
        float sf = sg ? oB : pB;
        float tg = sg ? pA : oA;
        float so = sg ? pB : oB;

        c = sf * c + si * tg;
        float h = so * tanh_fast(c);

        if (!sg) {
            reinterpret_cast<ushort*>(hpair[pp])[tid >> 1] =
                __builtin_bit_cast(ushort, (_Float16)h);
            feats[(size_t)(((b << 9) + t)) * 512 + (dir << 8) + (tid >> 1)] = h;
        }
        __syncthreads();
        r0 = hpair[pp][lane];
        r1 = hpair[pp][64 + lane];
        pp ^= 1;
        g = gnext;
    }
}

// ---------------------------------------------------------------------------
// emis_kernel: emissions[b,t,k] = feats[b,t,:] . W_out[k,:] + b_out[k]
// ---------------------------------------------------------------------------
__global__ __launch_bounds__(64) void emis_kernel(const float* __restrict__ feats,
                                                  const float* __restrict__ Wout,
                                                  const float* __restrict__ bout,
                                                  const int* __restrict__ lens,
                                                  float* __restrict__ emis) {
    int r = blockIdx.x;
    int b = r >> 9, t = r & 511;
    if (t >= lens[b]) return;
    int lane = threadIdx.x;
    const float* fr = feats + (size_t)r * 512;
    float f[8];
#pragma unroll
    for (int i = 0; i < 8; ++i) f[i] = fr[i * 64 + lane];
#pragma unroll
    for (int k = 0; k < 9; ++k) {
        float p = 0.0f;
#pragma unroll
        for (int i = 0; i < 8; ++i) p = fmaf(f[i], Wout[k * 512 + i * 64 + lane], p);
#pragma unroll
        for (int off = 32; off; off >>= 1) p += __shfl_down(p, off);
        if (lane == 0) emis[r * 9 + k] = p + bout[k];
    }
}

// ---------------------------------------------------------------------------
// crf_kernel: alpha recursion + viterbi + backtrace + numerator + loss.
// ---------------------------------------------------------------------------
__global__ __launch_bounds__(64) void crf_kernel(const float* __restrict__ emis,
                                                 const int* __restrict__ lens,
                                                 const int* __restrict__ labels,
                                                 const float* __restrict__ start_trans,
                                                 const float* __restrict__ end_trans,
                                                 const float* __restrict__ trans,
                                                 float* __restrict__ out) {
    int b = blockIdx.x;
    int len = lens[b];
    int lane = threadIdx.x;
    __shared__ float alpha[9], vit[9];
    __shared__ unsigned char hist[512 * 9];
    const float* eb = emis + b * 512 * 9;
    const int* lb = labels + b * 512;

    float tr[9];
    if (lane < 9) {
#pragma unroll
        for (int i = 0; i < 9; ++i) tr[i] = trans[i * 9 + lane];
        float s0 = start_trans[lane] + eb[lane];
        alpha[lane] = s0;
        vit[lane] = s0;
    }
    __syncthreads();

    for (int t = 1; t < len; ++t) {
        float na = 0.0f, nv = 0.0f;
        if (lane < 9) {
            float e = eb[t * 9 + lane];
            float a[9];
#pragma unroll
            for (int i = 0; i < 9; ++i) a[i] = alpha[i] + tr[i];
            float m = a[0];
#pragma unroll
            for (int i = 1; i < 9; ++i) m = fmaxf(m, a[i]);
            float s = 0.0f;
#pragma unroll
            for (int i = 0; i < 9; ++i) s += __expf(a[i] - m);
            na = m + __logf(s) + e;
            float bv = vit[0] + tr[0];
            int bi = 0;
#pragma unroll
            for (int i = 1; i < 9; ++i) {
                float x = vit[i] + tr[i];
                if (x > bv) { bv = x; bi = i; }
            }
            nv = bv + e;
            hist[t * 9 + lane] = (unsigned char)bi;
        }
        __syncthreads();
        if (lane < 9) { alpha[lane] = na; vit[lane] = nv; }
        __syncthreads();
    }

    float part = 0.0f;
    for (int t = 1 + lane; t < len; t += 64) {
        int yp = lb[t - 1], y = lb[t];
        part += trans[yp * 9 + y] + eb[t * 9 + y];
    }
#pragma unroll
    for (int off = 32; off; off >>= 1) part += __shfl_down(part, off);

    if (lane == 0) {
        int y0 = lb[0];
        float num = start_trans[y0] + eb[y0] + part + end_trans[lb[len - 1]];
        float m = alpha[0] + end_trans[0];
        for (int j = 1; j < 9; ++j) m = fmaxf(m, alpha[j] + end_trans[j]);
        float s = 0.0f;
        for (int j = 0; j < 9; ++j) s += __expf(alpha[j] + end_trans[j] - m);
        float denom = m + __logf(s);
        atomicAdd(out, (denom - num) * (1.0f / 64.0f));

        float bm = vit[0] + end_trans[0];
        int cur = 0;
        for (int j = 1; j < 9; ++j) {
            float x = vit[j] + end_trans[j];
            if (x > bm) { bm = x; cur = j; }
        }
        float* preds = out + 1 + b * 512;
        preds[len - 1] = (float)cur;
        for (int t = len - 1; t >= 1; --t) {
            cur = hist[t * 9 + cur];
            preds[t - 1] = (float)cur;
        }
    }
}

// ---------------------------------------------------------------------------
extern "C" void kernel_launch(void* const* d_in, const int* in_sizes, int n_in,
                              void* d_out, int out_size, void* d_ws, size_t ws_size,
                              hipStream_t stream) {
    const int* widx = (const int*)d_in[0];
    const int* lens = (const int*)d_in[1];
    const int* labels = (const int*)d_in[2];
    const float* wvec = (const float*)d_in[3];
    const float* WihF = (const float*)d_in[4];
    const float* WhhF = (const float*)d_in[5];
    const float* bF = (const float*)d_in[6];
    const float* WihB = (const float*)d_in[7];
    const float* WhhB = (const float*)d_in[8];
    const float* bB = (const float*)d_in[9];
    const float* Wout = (const float*)d_in[10];
    const float* bout = (const float*)d_in[11];
    const float* start_trans = (const float*)d_in[12];
    const float* end_trans = (const float*)d_in[13];
    const float* trans9 = (const float*)d_in[14];
    float* out = (float*)d_out;
    char* ws = (char*)d_ws;

    // workspace layout (bytes)
    _Float16* gxF = (_Float16*)(ws);                        // 67,108,864
    _Float16* gxB = (_Float16*)(ws + 67108864);             // 67,108,864
    uint* wregF   = (uint*)(ws + 134217728);                // 393,216
    uint* wregB   = (uint*)(ws + 134610944);                // 393,216
    uint* wldsF   = (uint*)(ws + 135004160);                // 131,072
    uint* wldsB   = (uint*)(ws + 135135232);                // 131,072
    // wih16F/B live only before lstm; emis written after lstm -> safe alias
    uint* wih16F  = (uint*)(ws + 135266304);                // 524,288
    uint* wih16B  = (uint*)(ws + 135790592);                // 524,288
    float* emis   = (float*)(ws + 135266304);               // 1,179,648 (alias)
    (void)in_sizes; (void)n_in; (void)out_size; (void)ws_size;

    float* feats = out + 1 + 32768;   // feats output region (B,T,512) fp32

    zero_kernel<<<65665, 256, 0, stream>>>(out, lens);
    pack_kernel<<<1024, 256, 0, stream>>>(WhhF, WhhB, wregF, wregB, wldsF, wldsB);
    wih_pack_kernel<<<1024, 256, 0, stream>>>(WihF, WihB, wih16F, wih16B);

    dim3 ggrid(512, 16);
    gemm_gx_kernel<<<ggrid, 256, 0, stream>>>(widx, lens, wvec, wih16F, bF, gxF);
    gemm_gx_kernel<<<ggrid, 256, 0, stream>>>(widx, lens, wvec, wih16B, bB, gxB);

    lstm_kernel<<<128, 512, 0, stream>>>(gxF, gxB, wregF, wregB, wldsF, wldsB, lens, feats);

    emis_kernel<<<32768, 64, 0, stream>>>(feats, Wout, bout, lens, emis);
    crf_kernel<<<64, 64, 0, stream>>>(emis, lens, labels, start_trans, end_trans, trans9, out);
}